// Round 5
// baseline (165.226 us; speedup 1.0000x reference)
//
#include <hip/hip_runtime.h>
#include <hip/hip_bf16.h>
#include <math.h>

// Problem dims (fixed by setup_inputs)
#define BB 4
#define LLEN 4096
#define HH 8
#define MM 256
#define KX 96          // padded x-dim: 64 qk + 8 fourier + [72]=hq(-1 col) + zeros
#define EE 80          // padded c-dim: 64 v + 1 ones + 15 zero
#define NTOK 16384     // BB*LLEN
#define NORM 0.35355339059327373f   // 64^-0.25 (folded into projB cols 0..63)
#define NORM2 0.125f                // NORM^2
#define LN16 2.7725887222397811f    // ln(sqrt(256)) folded into h => exp includes 1/sqrt(m)
#define EPSV 1e-6f
#define TWO_PI_F 6.283185307179586f
#define NSPLIT 16
#define PX_BLOCKS 2048

typedef __attribute__((ext_vector_type(8))) short s16x8;   // 8 bf16 (4 VGPRs)
typedef __attribute__((ext_vector_type(4))) short s16x4;   // 4 bf16
typedef __attribute__((ext_vector_type(2))) short s16x2;
typedef __attribute__((ext_vector_type(4))) float f32x4;   // MFMA acc

#define MFMA16(A,B,C) __builtin_amdgcn_mfma_f32_16x16x32_bf16(A,B,C,0,0,0)

static __device__ __forceinline__ unsigned short f2bf(float f) {
  union { float f; unsigned int u; } v; v.f = f;
  unsigned int r = v.u + 0x7FFFu + ((v.u >> 16) & 1u);   // round-to-nearest-even
  return (unsigned short)(r >> 16);
}

// ---- workspace byte offsets ----
#define OFF_PROJB 0u
#define OFF_XQ    49152u
#define OFF_XK    (OFF_XQ + 25165824u)
#define OFF_HQ    (OFF_XK + 25165824u)   // unused (kept for layout stability)
#define OFF_HK    (OFF_HQ + 524288u)
#define OFF_VST   (OFF_HK + 524288u)
#define OFF_PARTS (OFF_VST + 20971520u)
#define OFF_B1T   (OFF_PARTS + 41943040u)

// ---------------------------------------------------------------------------
// projB[m][0..95] bf16: 0..63 = proj*NORM, 64..71 = proj, 72 = -1 (hq fold),
// 73..95 = 0
// ---------------------------------------------------------------------------
__global__ __launch_bounds__(256) void prep_proj(const float* __restrict__ proj,
                                                 unsigned short* __restrict__ projB) {
  int m = threadIdx.x;
#pragma unroll
  for (int d = 0; d < 64; ++d) projB[m * KX + d] = f2bf(proj[m * 72 + d] * NORM);
#pragma unroll
  for (int d = 64; d < 72; ++d) projB[m * KX + d] = f2bf(proj[m * 72 + d]);
  projB[m * KX + 72] = 0xBF80;   // bf16(-1)
#pragma unroll
  for (int d = 73; d < 96; ++d) projB[m * KX + d] = 0;
}

// ---------------------------------------------------------------------------
// prep_x: wave-cooperative, fully coalesced. 16 lanes per (row = token*8+h,
// side). X layout: [h][token][96] bf16. q-side col 72 = bf16(hq) (paired with
// projB col72 = -1 => GEMM1 computes s - hq directly; rounding cancels in
// num/den). k-side col 72 = 0; hkp[h][token] kept in f32.
// ---------------------------------------------------------------------------
__global__ __launch_bounds__(256) void prep_x(
    const float* __restrict__ qs, const float* __restrict__ ks,
    const float* __restrict__ qs_s, const float* __restrict__ ks_s,
    const float* __restrict__ W, const float* __restrict__ a,
    unsigned short* __restrict__ Xq, unsigned short* __restrict__ Xk,
    float* __restrict__ hkp) {
  const int NW_TOT = PX_BLOCKS * 4;                 // 8192 waves
  int wid = blockIdx.x * 4 + (threadIdx.x >> 6);
  int l = threadIdx.x & 63;
  int l15 = l & 15, g = l >> 4;

  for (int qd = wid; qd < 65536; qd += NW_TOT) {
    int row = qd * 4 + g;                           // 0..262143
    bool isq = row < 131072;
    int t = isq ? row : row - 131072;               // token*8 + h
    int token = t >> 3, h = t & 7;
    const float* src = (isq ? qs : ks) + (size_t)t * 64;
    unsigned short* dst = (isq ? Xq : Xk) + ((size_t)h * NTOK + token) * KX;

    f32x4 v = *reinterpret_cast<const f32x4*>(src + 4 * l15);
    float ss = v[0] * v[0] + v[1] * v[1] + v[2] * v[2] + v[3] * v[3];
    s16x4 o;
#pragma unroll
    for (int i = 0; i < 4; ++i) o[i] = (short)f2bf(v[i]);
    *reinterpret_cast<s16x4*>(dst + 4 * l15) = o;

    float contrib = ss * NORM2;
    if (l15 < 8) {
      float sv = (isq ? qs_s : ks_s)[token] * TWO_PI_F;
      int dim = 8 * h + l15;
      float ph = sv * W[dim & 31];
      float e = (dim < 32) ? sinf(ph) : cosf(ph);
      if (isq) e *= a[h];
      contrib += e * e;
      dst[64 + l15] = f2bf(e);
    }
    if (l15 > 0 && l15 < 12) {
      s16x2 z = {};
      *reinterpret_cast<s16x2*>(dst + 72 + 2 * l15) = z;
    }
#pragma unroll
    for (int m = 1; m < 16; m <<= 1) contrib += __shfl_xor(contrib, m, 64);
    if (l15 == 0) {
      float hval = 0.5f * contrib + LN16;
      s16x2 hz;
      hz[0] = isq ? (short)f2bf(hval) : (short)0;
      hz[1] = 0;
      *reinterpret_cast<s16x2*>(dst + 72) = hz;
      if (!isq) hkp[h * NTOK + token] = hval;
    }
  }
}

// ---------------------------------------------------------------------------
// vsT[bh][e][k] bf16 for e<64 via LDS tile transpose (rows 64..79 by prep_fill)
// ---------------------------------------------------------------------------
__global__ __launch_bounds__(256) void prep_vst(const float* __restrict__ vs,
                                                unsigned short* __restrict__ vsT) {
  int kc = blockIdx.x;   // 0..63
  int bh = blockIdx.y;   // 0..31
  int b = bh >> 3, h = bh & 7;
  int t = threadIdx.x;
  __shared__ unsigned short tile[64][72];
  int k = t >> 2, seg = t & 3;
  const f32x4* src = reinterpret_cast<const f32x4*>(
      vs + (((size_t)(b * LLEN + kc * 64 + k)) * HH + h) * 64 + seg * 16);
#pragma unroll
  for (int j = 0; j < 4; ++j) {
    f32x4 v = src[j];
#pragma unroll
    for (int i = 0; i < 4; ++i) tile[k][seg * 16 + j * 4 + i] = f2bf(v[i]);
  }
  __syncthreads();
  int e = t >> 2, ksg = t & 3;
  s16x8 o0, o1;
#pragma unroll
  for (int j = 0; j < 8; ++j) o0[j] = (short)tile[ksg * 16 + j][e];
#pragma unroll
  for (int j = 0; j < 8; ++j) o1[j] = (short)tile[ksg * 16 + 8 + j][e];
  unsigned short* dst = vsT + ((size_t)bh * EE + e) * LLEN + kc * 64 + ksg * 16;
  *reinterpret_cast<s16x8*>(dst) = o0;
  *reinterpret_cast<s16x8*>(dst + 8) = o1;
}

__global__ __launch_bounds__(256) void prep_fill(unsigned short* __restrict__ vsT) {
  int t = blockIdx.x * 256 + threadIdx.x;
  int f0 = t * 8;
  int bh = f0 >> 16;
  int rem = f0 & 65535;
  int er = rem >> 12;
  int k = rem & 4095;
  unsigned short val = (er == 0) ? f2bf(1.0f) : (unsigned short)0;
  s16x8 v;
#pragma unroll
  for (int i = 0; i < 8; ++i) v[i] = (short)val;
  *reinterpret_cast<s16x8*>(vsT + ((size_t)bh * EE + 64 + er) * LLEN + k) = v;
}

// ---------------------------------------------------------------------------
// F1: fused phi_k GEMM + exp + buf1 GEMM, register pipeline, m-split x2.
// grid (32 bh, 32 = 16 splits x 2 m-halves), wave owns 2 m-tiles.
// Xk double-buffered (streaming operand); vsT/hk issued at iter top.
// ---------------------------------------------------------------------------
__global__ __launch_bounds__(256, 2) void f1_k(
    const unsigned short* __restrict__ Xk, const unsigned short* __restrict__ projB,
    const unsigned short* __restrict__ vsT, const float* __restrict__ hkp,
    float* __restrict__ parts) {
  int bh = blockIdx.x;
  int split = blockIdx.y >> 1, mh = blockIdx.y & 1;
  int b = bh >> 3, h = bh & 7;
  int w = threadIdx.x >> 6, l = threadIdx.x & 63;
  int l15 = l & 15, l4 = l >> 4;
  int mt0 = mh * 8 + 2 * w;          // wave's first m-tile (of 16)

  s16x8 pb[2][3];
#pragma unroll
  for (int nt = 0; nt < 2; ++nt)
#pragma unroll
    for (int ks = 0; ks < 3; ++ks)
      pb[nt][ks] = *reinterpret_cast<const s16x8*>(
          projB + (size_t)(l15 + 16 * (mt0 + nt)) * KX + 32 * ks + 8 * l4);

  f32x4 acc2[2][5] = {};
  const float* hkb = hkp + h * NTOK + b * LLEN;
  const unsigned short* xkb = Xk + ((size_t)h * NTOK + b * LLEN) * KX;
  int kbase = split * 256;

  s16x8 ak[2][3];
#pragma unroll
  for (int ks = 0; ks < 3; ++ks) {
    ak[0][ks] = *reinterpret_cast<const s16x8*>(
        xkb + (size_t)(kbase + l15) * KX + 32 * ks + 8 * l4);
    ak[1][ks] = *reinterpret_cast<const s16x8*>(
        xkb + (size_t)(kbase + 16 + l15) * KX + 32 * ks + 8 * l4);
  }

#pragma unroll
  for (int it = 0; it < 8; ++it) {
    int k0 = kbase + it * 32;
    s16x8 an[2][3];
    if (it < 7) {
#pragma unroll
      for (int ks = 0; ks < 3; ++ks) {
        an[0][ks] = *reinterpret_cast<const s16x8*>(
            xkb + (size_t)(k0 + 32 + l15) * KX + 32 * ks + 8 * l4);
        an[1][ks] = *reinterpret_cast<const s16x8*>(
            xkb + (size_t)(k0 + 48 + l15) * KX + 32 * ks + 8 * l4);
      }
    }
    f32x4 hk0 = *reinterpret_cast<const f32x4*>(hkb + k0 + 4 * l4);
    f32x4 hk1 = *reinterpret_cast<const f32x4*>(hkb + k0 + 16 + 4 * l4);

    f32x4 acc1[2][2] = {};
#pragma unroll
    for (int ks = 0; ks < 3; ++ks)
#pragma unroll
      for (int nt = 0; nt < 2; ++nt) {
        acc1[0][nt] = MFMA16(ak[0][ks], pb[nt][ks], acc1[0][nt]);
        acc1[1][nt] = MFMA16(ak[1][ks], pb[nt][ks], acc1[1][nt]);
      }
    s16x8 pa[2];
#pragma unroll
    for (int nt = 0; nt < 2; ++nt)
#pragma unroll
      for (int r = 0; r < 4; ++r) {
        pa[nt][r]     = (short)f2bf(__expf(acc1[0][nt][r] - hk0[r]));
        pa[nt][4 + r] = (short)f2bf(__expf(acc1[1][nt][r] - hk1[r]));
      }
#pragma unroll
    for (int ne = 0; ne < 5; ++ne) {
      const unsigned short* vp =
          vsT + ((size_t)bh * EE + l15 + 16 * ne) * LLEN + k0 + 4 * l4;
      s16x4 v0 = *reinterpret_cast<const s16x4*>(vp);
      s16x4 v1 = *reinterpret_cast<const s16x4*>(vp + 16);
      s16x8 vb;
#pragma unroll
      for (int i = 0; i < 4; ++i) { vb[i] = v0[i]; vb[4 + i] = v1[i]; }
#pragma unroll
      for (int nt = 0; nt < 2; ++nt)
        acc2[nt][ne] = MFMA16(pa[nt], vb, acc2[nt][ne]);
    }
    if (it < 7) {
#pragma unroll
      for (int ks = 0; ks < 3; ++ks) { ak[0][ks] = an[0][ks]; ak[1][ks] = an[1][ks]; }
    }
  }
#pragma unroll
  for (int nt = 0; nt < 2; ++nt)
#pragma unroll
    for (int ne = 0; ne < 5; ++ne)
#pragma unroll
      for (int r = 0; r < 4; ++r) {
        int m = 16 * (mt0 + nt) + 4 * l4 + r;
        parts[(((size_t)split * 32 + bh) * MM + m) * EE + l15 + 16 * ne] = acc2[nt][ne][r];
      }
}

// ---------------------------------------------------------------------------
// reduce 16 splits -> buf1T bf16 [bh][80 e][256 m]
// ---------------------------------------------------------------------------
__global__ __launch_bounds__(256) void reduce_t(const float* __restrict__ parts,
                                                unsigned short* __restrict__ b1T) {
  int bh = blockIdx.x;   // 32
  int mc = blockIdx.y;   // 4 (64 m each)
  __shared__ float s[64 * 80];
  size_t base = ((size_t)bh * MM + mc * 64) * EE;
  for (int o = threadIdx.x; o < 64 * 80; o += 256) {
    float sum = 0.f;
#pragma unroll
    for (int sp = 0; sp < 16; ++sp)
      sum += parts[(size_t)sp * 32 * MM * EE + base + o];
    s[o] = sum;
  }
  __syncthreads();
  for (int o = threadIdx.x; o < 64 * 80; o += 256) {
    int e = o >> 6, ml = o & 63;
    b1T[((size_t)bh * EE + e) * MM + mc * 64 + ml] = f2bf(s[ml * 80 + e]);
  }
}

// ---------------------------------------------------------------------------
// F2: fused phi_q GEMM + exp + output GEMM, register pipeline.
// projB double-buffered one m-block ahead; hq folded into GEMM via col 72.
// ---------------------------------------------------------------------------
__global__ __launch_bounds__(256, 3) void f2_k(
    const unsigned short* __restrict__ Xq, const unsigned short* __restrict__ projB,
    const unsigned short* __restrict__ b1T, float* __restrict__ out) {
  int bh = blockIdx.x, qc = blockIdx.y;
  int b = bh >> 3, h = bh & 7;
  int w = threadIdx.x >> 6, l = threadIdx.x & 63;
  int l15 = l & 15, l4 = l >> 4;
  int qb = qc * 128 + w * 32;   // wave's 32 queries
  const unsigned short* xqb = Xq + ((size_t)h * NTOK + b * LLEN) * KX;

  s16x8 xq[2][3];
#pragma unroll
  for (int qt = 0; qt < 2; ++qt)
#pragma unroll
    for (int xs = 0; xs < 3; ++xs)
      xq[qt][xs] = *reinterpret_cast<const s16x8*>(
          xqb + (size_t)(qb + 16 * qt + l15) * KX + 32 * xs + 8 * l4);

  s16x8 pc0[3], pc1[3];
#pragma unroll
  for (int xs = 0; xs < 3; ++xs) {
    pc0[xs] = *reinterpret_cast<const s16x8*>(
        projB + (size_t)(l15) * KX + 32 * xs + 8 * l4);
    pc1[xs] = *reinterpret_cast<const s16x8*>(
        projB + (size_t)(l15 + 16) * KX + 32 * xs + 8 * l4);
  }

  f32x4 acc3[2][5] = {};
#pragma unroll
  for (int ks = 0; ks < 8; ++ks) {   // m-block of 32
    s16x8 pn0[3], pn1[3];
    if (ks < 7) {
#pragma unroll
      for (int xs = 0; xs < 3; ++xs) {
        pn0[xs] = *reinterpret_cast<const s16x8*>(
            projB + (size_t)(l15 + 16 * (2 * ks + 2)) * KX + 32 * xs + 8 * l4);
        pn1[xs] = *reinterpret_cast<const s16x8*>(
            projB + (size_t)(l15 + 16 * (2 * ks + 3)) * KX + 32 * xs + 8 * l4);
      }
    }
    f32x4 a0 = {}, b0 = {}, a1 = {}, b1 = {};
#pragma unroll
    for (int xs = 0; xs < 3; ++xs) {
      a0 = MFMA16(pc0[xs], xq[0][xs], a0);
      b0 = MFMA16(pc1[xs], xq[0][xs], b0);
      a1 = MFMA16(pc0[xs], xq[1][xs], a1);
      b1 = MFMA16(pc1[xs], xq[1][xs], b1);
    }
    s16x8 pa0, pa1;
#pragma unroll
    for (int r = 0; r < 4; ++r) {
      pa0[r]     = (short)f2bf(__expf(a0[r]));
      pa0[4 + r] = (short)f2bf(__expf(b0[r]));
      pa1[r]     = (short)f2bf(__expf(a1[r]));
      pa1[4 + r] = (short)f2bf(__expf(b1[r]));
    }
#pragma unroll
    for (int ne = 0; ne < 5; ++ne) {
      const unsigned short* vp =
          b1T + ((size_t)bh * EE + l15 + 16 * ne) * MM + 32 * ks + 4 * l4;
      s16x4 v0 = *reinterpret_cast<const s16x4*>(vp);
      s16x4 v1 = *reinterpret_cast<const s16x4*>(vp + 16);
      s16x8 vb;
#pragma unroll
      for (int i = 0; i < 4; ++i) { vb[i] = v0[i]; vb[4 + i] = v1[i]; }
      acc3[0][ne] = MFMA16(pa0, vb, acc3[0][ne]);
      acc3[1][ne] = MFMA16(pa1, vb, acc3[1][ne]);
    }
    if (ks < 7) {
#pragma unroll
      for (int xs = 0; xs < 3; ++xs) { pc0[xs] = pn0[xs]; pc1[xs] = pn1[xs]; }
    }
  }
#pragma unroll
  for (int qt = 0; qt < 2; ++qt) {
    float inv[4];
#pragma unroll
    for (int r = 0; r < 4; ++r) {
      float den = __shfl(acc3[qt][4][r], 16 * l4, 64);   // e=64 lives in lanes l15==0
      den = den < EPSV ? EPSV : den;
      inv[r] = 1.0f / den;
    }
#pragma unroll
    for (int ne = 0; ne < 4; ++ne)
#pragma unroll
      for (int r = 0; r < 4; ++r)
        out[((size_t)(b * LLEN + qb + 16 * qt + 4 * l4 + r) * HH + h) * 64 + l15 + 16 * ne] =
            acc3[qt][ne][r] * inv[r];
  }
}

// ---------------------------------------------------------------------------
extern "C" void kernel_launch(void* const* d_in, const int* in_sizes, int n_in,
                              void* d_out, int out_size, void* d_ws, size_t ws_size,
                              hipStream_t stream) {
  const float* qs   = (const float*)d_in[0];
  const float* ks   = (const float*)d_in[1];
  const float* vs   = (const float*)d_in[2];
  const float* qs_s = (const float*)d_in[3];
  const float* ks_s = (const float*)d_in[4];
  const float* W    = (const float*)d_in[5];
  const float* proj = (const float*)d_in[6];
  const float* a    = (const float*)d_in[7];
  float* out = (float*)d_out;

  char* ws = (char*)d_ws;
  unsigned short* projB = (unsigned short*)(ws + OFF_PROJB);
  unsigned short* Xq    = (unsigned short*)(ws + OFF_XQ);
  unsigned short* Xk    = (unsigned short*)(ws + OFF_XK);
  float*          hkp   = (float*)(ws + OFF_HK);
  unsigned short* vsT   = (unsigned short*)(ws + OFF_VST);
  float*          parts = (float*)(ws + OFF_PARTS);
  unsigned short* b1T   = (unsigned short*)(ws + OFF_B1T);

  prep_proj<<<1, 256, 0, stream>>>(proj, projB);
  prep_x<<<PX_BLOCKS, 256, 0, stream>>>(qs, ks, qs_s, ks_s, W, a, Xq, Xk, hkp);
  prep_vst<<<dim3(64, 32), 256, 0, stream>>>(vs, vsT);
  prep_fill<<<1024, 256, 0, stream>>>(vsT);
  f1_k<<<dim3(32, 32), 256, 0, stream>>>(Xk, projB, vsT, hkp, parts);
  reduce_t<<<dim3(32, 4), 256, 0, stream>>>(parts, b1T);
  f2_k<<<dim3(32, 32), 256, 0, stream>>>(Xq, projB, b1T, out);
}

// Round 6
// 113.895 us; speedup vs baseline: 1.4507x; 1.4507x over previous
//
#include <hip/hip_runtime.h>
#include <hip/hip_bf16.h>
#include <math.h>

// Problem dims (fixed by setup_inputs)
#define BB 4
#define LLEN 4096
#define HH 8
#define MM 256
#define KX 96          // padded x-dim: 64 qk + 8 fourier + [72]=hq(-1 col) + zeros
#define EE 80          // padded c-dim: 64 v + 1 ones + 15 zero
#define NTOK 16384     // BB*LLEN
#define NORM 0.35355339059327373f   // 64^-0.25 (folded into projF cols 0..63)
#define NORM2 0.125f                // NORM^2
#define LN16 2.7725887222397811f    // ln(sqrt(256)) folded into h => exp includes 1/sqrt(m)
#define EPSV 1e-6f
#define TWO_PI_F 6.283185307179586f
#define PX_BLOCKS 2048

typedef __attribute__((ext_vector_type(8))) short s16x8;   // 8 bf16 (4 VGPRs)
typedef __attribute__((ext_vector_type(4))) short s16x4;   // 4 bf16
typedef __attribute__((ext_vector_type(2))) short s16x2;
typedef __attribute__((ext_vector_type(4))) float f32x4;   // MFMA acc
typedef __attribute__((ext_vector_type(4))) unsigned int u32x4;

#define MFMA16(A,B,C) __builtin_amdgcn_mfma_f32_16x16x32_bf16(A,B,C,0,0,0)

static __device__ __forceinline__ unsigned short f2bf(float f) {
  union { float f; unsigned int u; } v; v.f = f;
  unsigned int r = v.u + 0x7FFFu + ((v.u >> 16) & 1u);   // round-to-nearest-even
  return (unsigned short)(r >> 16);
}

// ---- workspace byte offsets (total ~116 MB) ----
#define OFF_PROJF 0u
#define OFF_XQ    49152u
#define OFF_XK    (OFF_XQ + 25165824u)
#define OFF_HQ    (OFF_XK + 25165824u)   // unused slot
#define OFF_HK    (OFF_HQ + 524288u)
#define OFF_VF    (OFF_HK + 524288u)     // 20971520 B
#define OFF_PARTS (OFF_VF + 20971520u)   // 41943040 B
#define OFF_B1F   (OFF_PARTS + 41943040u) // 1310720 B

// ---------------------------------------------------------------------------
// projF fragment-major: chunk c = mt*3+xs (48 chunks), lane l, j=0..7:
//   value = projLogical[(l&15)+16*mt][32*xs+8*(l>>4)+j]
// projLogical[m][d] = d<64: proj[m][d]*NORM; d<72: proj[m][d]; d==72: -1; else 0
// ---------------------------------------------------------------------------
__global__ __launch_bounds__(256) void prep_projF(const float* __restrict__ proj,
                                                  unsigned short* __restrict__ projF) {
  int t = threadIdx.x;
  int l = t & 63, grp = t >> 6;
  int l15 = l & 15, l4 = l >> 4;
  for (int c = grp; c < 48; c += 4) {
    int mt = c / 3, xs = c % 3;
    int m = l15 + 16 * mt;
    s16x8 o;
#pragma unroll
    for (int j = 0; j < 8; ++j) {
      int d = 32 * xs + 8 * l4 + j;
      unsigned short u;
      if (d < 64)      u = f2bf(proj[m * 72 + d] * NORM);
      else if (d < 72) u = f2bf(proj[m * 72 + d]);
      else if (d == 72) u = 0xBF80;  // bf16(-1): pairs with Xq col72 = hq
      else             u = 0;
      o[j] = (short)u;
    }
    *reinterpret_cast<s16x8*>(projF + ((size_t)c * 64 + l) * 8) = o;
  }
}

// ---------------------------------------------------------------------------
// prep_x (unchanged, proven): X layout [h][token][96] bf16; q col72 = hq,
// k col72 = 0; hkp[h][token] f32.
// ---------------------------------------------------------------------------
__global__ __launch_bounds__(256) void prep_x(
    const float* __restrict__ qs, const float* __restrict__ ks,
    const float* __restrict__ qs_s, const float* __restrict__ ks_s,
    const float* __restrict__ W, const float* __restrict__ a,
    unsigned short* __restrict__ Xq, unsigned short* __restrict__ Xk,
    float* __restrict__ hkp) {
  const int NW_TOT = PX_BLOCKS * 4;
  int wid = blockIdx.x * 4 + (threadIdx.x >> 6);
  int l = threadIdx.x & 63;
  int l15 = l & 15, g = l >> 4;

  for (int qd = wid; qd < 65536; qd += NW_TOT) {
    int row = qd * 4 + g;
    bool isq = row < 131072;
    int t = isq ? row : row - 131072;
    int token = t >> 3, h = t & 7;
    const float* src = (isq ? qs : ks) + (size_t)t * 64;
    unsigned short* dst = (isq ? Xq : Xk) + ((size_t)h * NTOK + token) * KX;

    f32x4 v = *reinterpret_cast<const f32x4*>(src + 4 * l15);
    float ss = v[0] * v[0] + v[1] * v[1] + v[2] * v[2] + v[3] * v[3];
    s16x4 o;
#pragma unroll
    for (int i = 0; i < 4; ++i) o[i] = (short)f2bf(v[i]);
    *reinterpret_cast<s16x4*>(dst + 4 * l15) = o;

    float contrib = ss * NORM2;
    if (l15 < 8) {
      float sv = (isq ? qs_s : ks_s)[token] * TWO_PI_F;
      int dim = 8 * h + l15;
      float ph = sv * W[dim & 31];
      float e = (dim < 32) ? sinf(ph) : cosf(ph);
      if (isq) e *= a[h];
      contrib += e * e;
      dst[64 + l15] = f2bf(e);
    }
    if (l15 > 0 && l15 < 12) {
      s16x2 z = {};
      *reinterpret_cast<s16x2*>(dst + 72 + 2 * l15) = z;
    }
#pragma unroll
    for (int m = 1; m < 16; m <<= 1) contrib += __shfl_xor(contrib, m, 64);
    if (l15 == 0) {
      float hval = 0.5f * contrib + LN16;
      s16x2 hz;
      hz[0] = isq ? (short)f2bf(hval) : (short)0;
      hz[1] = 0;
      *reinterpret_cast<s16x2*>(dst + 72) = hz;
      if (!isq) hkp[h * NTOK + token] = hval;
    }
  }
}

// ---------------------------------------------------------------------------
// vF fragment-major: [bh][kslot(128)][ne(5)][lane][8]:
//   value = c[e=(l&15)+16ne][k = 32*kslot + 16*(j>>2) + 4*(l>>4) + (j&3)]
//   c[e][k] = e<64 ? bf16(vs[b,k,h,e]) : (e==64 ? 1 : 0)
// ---------------------------------------------------------------------------
__global__ __launch_bounds__(256) void prep_vF(const float* __restrict__ vs,
                                               unsigned short* __restrict__ vF) {
  int kc = blockIdx.x;   // 0..63 (64-key chunk)
  int bh = blockIdx.y;   // 0..31
  int b = bh >> 3, h = bh & 7;
  int t = threadIdx.x;
  __shared__ unsigned short tile[64][72];
  int k = t >> 2, seg = t & 3;
  const f32x4* src = reinterpret_cast<const f32x4*>(
      vs + (((size_t)(b * LLEN + kc * 64 + k)) * HH + h) * 64 + seg * 16);
#pragma unroll
  for (int j = 0; j < 4; ++j) {
    f32x4 v = src[j];
#pragma unroll
    for (int i = 0; i < 4; ++i) tile[k][seg * 16 + j * 4 + i] = f2bf(v[i]);
  }
  __syncthreads();
  int l = t & 63, ks2 = (t >> 6) & 1, rep = t >> 7;
  int l15 = l & 15, l4 = l >> 4;
  int nelo = rep ? 3 : 0, nehi = rep ? 5 : 3;
  for (int ne = nelo; ne < nehi; ++ne) {
    int e = l15 + 16 * ne;
    s16x8 o;
#pragma unroll
    for (int j = 0; j < 8; ++j) {
      int kl = 32 * ks2 + 16 * (j >> 2) + 4 * l4 + (j & 3);
      unsigned short u;
      if (e < 64)       u = tile[kl][e];
      else if (e == 64) u = 0x3F80;  // bf16(1.0)
      else              u = 0;
      o[j] = (short)u;
    }
    size_t kslot = (size_t)kc * 2 + ks2;
    *reinterpret_cast<s16x8*>(
        vF + (((size_t)bh * 128 + kslot) * 5 + ne) * 64 * 8 + (size_t)l * 8) = o;
  }
}

// ---------------------------------------------------------------------------
// F1: fused phi_k GEMM + exp + buf1 GEMM. 512 threads (8 waves, 2 mt each).
// LDS: projF 48K + vF slice 40K (staged once) + Xk dbuf 2x8K (per-iter,
// XOR-swizzled pitch-256 rows). 1 barrier/iter. grid (32 bh, 16 splits).
// ---------------------------------------------------------------------------
__global__ __launch_bounds__(512, 2) void f1_k(
    const unsigned short* __restrict__ Xk, const unsigned short* __restrict__ projF,
    const unsigned short* __restrict__ vF, const float* __restrict__ hkp,
    float* __restrict__ parts) {
  __shared__ unsigned short pf_lds[24576];       // 48 KB
  __shared__ unsigned short vf_lds[20480];       // 40 KB
  __shared__ unsigned char  xk_lds[2][8192];     // 16 KB (32 rows x 256 B)

  int bh = blockIdx.x, split = blockIdx.y;
  int b = bh >> 3, h = bh & 7;
  int tid = threadIdx.x;
  int w = tid >> 6, l = tid & 63;
  int l15 = l & 15, l4 = l >> 4;
  int kbase = split * 256;

  const unsigned short* xkb = Xk + ((size_t)h * NTOK + b * LLEN) * KX;
  const float* hkb = hkp + h * NTOK + b * LLEN;

  // ---- stage projF + vF slice + Xk tile 0 ----
  {
    const u32x4* g1 = reinterpret_cast<const u32x4*>(projF);
    u32x4* s1 = reinterpret_cast<u32x4*>(pf_lds);
#pragma unroll
    for (int i = 0; i < 6; ++i) s1[i * 512 + tid] = g1[i * 512 + tid];
    const u32x4* g2 = reinterpret_cast<const u32x4*>(
        vF + ((size_t)bh * 128 + split * 8) * 5 * 64 * 8);
    u32x4* s2 = reinterpret_cast<u32x4*>(vf_lds);
#pragma unroll
    for (int i = 0; i < 5; ++i) s2[i * 512 + tid] = g2[i * 512 + tid];
    if (tid < 384) {
      u32x4 x0 = reinterpret_cast<const u32x4*>(xkb + (size_t)kbase * KX)[tid];
      int row = tid / 12;
      int c = tid * 16 - row * 192;
      *reinterpret_cast<u32x4*>(&xk_lds[0][row * 256 + (c ^ ((row & 7) << 4))]) = x0;
    }
  }
  __syncthreads();

  f32x4 acc2[2][5] = {};

  for (int it = 0; it < 8; ++it) {
    int k0 = kbase + it * 32;
    int cur = it & 1, nxt = cur ^ 1;
    // prefetch next Xk tile to regs (T14: issue early, write late)
    u32x4 nx;
    if (it < 7 && tid < 384)
      nx = reinterpret_cast<const u32x4*>(xkb + (size_t)(k0 + 32) * KX)[tid];
    f32x4 hk0 = *reinterpret_cast<const f32x4*>(hkb + k0 + 4 * l4);
    f32x4 hk1 = *reinterpret_cast<const f32x4*>(hkb + k0 + 16 + 4 * l4);

    // ---- GEMM1: P = Xk . projF^T ----
    s16x8 ak0[3], ak1[3], pf0[3], pf1[3];
#pragma unroll
    for (int xs = 0; xs < 3; ++xs) {
      int co = (64 * xs + 16 * l4) ^ ((l15 & 7) << 4);
      ak0[xs] = *reinterpret_cast<const s16x8*>(&xk_lds[cur][l15 * 256 + co]);
      ak1[xs] = *reinterpret_cast<const s16x8*>(&xk_lds[cur][(16 + l15) * 256 + co]);
      pf0[xs] = *reinterpret_cast<const s16x8*>(pf_lds + (((2 * w) * 3 + xs) * 64 + l) * 8);
      pf1[xs] = *reinterpret_cast<const s16x8*>(pf_lds + (((2 * w + 1) * 3 + xs) * 64 + l) * 8);
    }
    f32x4 acc1[2][2] = {};
#pragma unroll
    for (int xs = 0; xs < 3; ++xs) {
      acc1[0][0] = MFMA16(ak0[xs], pf0[xs], acc1[0][0]);
      acc1[0][1] = MFMA16(ak0[xs], pf1[xs], acc1[0][1]);
      acc1[1][0] = MFMA16(ak1[xs], pf0[xs], acc1[1][0]);
      acc1[1][1] = MFMA16(ak1[xs], pf1[xs], acc1[1][1]);
    }
    // ---- exp -> bf16 A-frag (k-perm: slot(l4,j) <-> key 16(j>>2)+4l4+(j&3)) ----
    s16x8 pa[2];
#pragma unroll
    for (int nt = 0; nt < 2; ++nt)
#pragma unroll
      for (int r = 0; r < 4; ++r) {
        pa[nt][r]     = (short)f2bf(__expf(acc1[0][nt][r] - hk0[r]));
        pa[nt][4 + r] = (short)f2bf(__expf(acc1[1][nt][r] - hk1[r]));
      }
    // ---- GEMM2: acc2 += P^T . c ----
#pragma unroll
    for (int ne = 0; ne < 5; ++ne) {
      s16x8 vb = *reinterpret_cast<const s16x8*>(vf_lds + ((it * 5 + ne) * 64 + l) * 8);
      acc2[0][ne] = MFMA16(pa[0], vb, acc2[0][ne]);
      acc2[1][ne] = MFMA16(pa[1], vb, acc2[1][ne]);
    }
    // ---- write next tile, barrier ----
    if (it < 7 && tid < 384) {
      int row = tid / 12;
      int c = tid * 16 - row * 192;
      *reinterpret_cast<u32x4*>(&xk_lds[nxt][row * 256 + (c ^ ((row & 7) << 4))]) = nx;
    }
    __syncthreads();
  }

#pragma unroll
  for (int nt = 0; nt < 2; ++nt)
#pragma unroll
    for (int ne = 0; ne < 5; ++ne)
#pragma unroll
      for (int r = 0; r < 4; ++r) {
        int m = 16 * (2 * w + nt) + 4 * l4 + r;
        parts[(((size_t)split * 32 + bh) * MM + m) * EE + l15 + 16 * ne] = acc2[nt][ne][r];
      }
}

// ---------------------------------------------------------------------------
// reduce 16 splits -> b1F fragment-major [bh][ks(8)][ne(5)][lane][8] bf16
// ---------------------------------------------------------------------------
__global__ __launch_bounds__(256) void reduce_t(const float* __restrict__ parts,
                                                unsigned short* __restrict__ b1F) {
  int bh = blockIdx.x;   // 32
  int mc = blockIdx.y;   // 4 (64 m each)
  __shared__ float s[64 * 80];
  size_t base = ((size_t)bh * MM + mc * 64) * EE;
  for (int o = threadIdx.x; o < 64 * 80; o += 256) {
    float sum = 0.f;
#pragma unroll
    for (int sp = 0; sp < 16; ++sp)
      sum += parts[(size_t)sp * 32 * MM * EE + base + o];
    s[o] = sum;
  }
  __syncthreads();
  int t = threadIdx.x, l = t & 63, kl = (t >> 6) & 1, rep = t >> 7;
  int l15 = l & 15, l4 = l >> 4;
  int nelo = rep ? 3 : 0, nehi = rep ? 5 : 3;
  for (int ne = nelo; ne < nehi; ++ne) {
    s16x8 o;
#pragma unroll
    for (int j = 0; j < 8; ++j) {
      int ml = 32 * kl + 16 * (j >> 2) + 4 * l4 + (j & 3);
      o[j] = (short)f2bf(s[ml * 80 + l15 + 16 * ne]);
    }
    int ks = mc * 2 + kl;
    *reinterpret_cast<s16x8*>(
        b1F + (((size_t)bh * 8 + ks) * 5 + ne) * 64 * 8 + (size_t)l * 8) = o;
  }
}

// ---------------------------------------------------------------------------
// F2: fused phi_q GEMM + exp + output GEMM. 512 threads (8 waves x 32 q).
// LDS: projF 48K + b1F 40K staged once; inner loop is pure ds_read+MFMA+exp,
// zero global loads, zero barriers. grid (32 bh, 16 qc of 256 queries).
// ---------------------------------------------------------------------------
__global__ __launch_bounds__(512, 2) void f2_k(
    const unsigned short* __restrict__ Xq, const unsigned short* __restrict__ projF,
    const unsigned short* __restrict__ b1F, float* __restrict__ out) {
  __shared__ unsigned short pf_lds[24576];   // 48 KB
  __shared__ unsigned short b1_lds[20480];   // 40 KB

  int bh = blockIdx.x, qc = blockIdx.y;
  int b = bh >> 3, h = bh & 7;
  int tid = threadIdx.x;
  int w = tid >> 6, l = tid & 63;
  int l15 = l & 15, l4 = l >> 4;
  int qb = qc * 256 + w * 32;

  // stage projF + b1F(bh)
  {
    const u32x4* g1 = reinterpret_cast<const u32x4*>(projF);
    u32x4* s1 = reinterpret_cast<u32x4*>(pf_lds);
#pragma unroll
    for (int i = 0; i < 6; ++i) s1[i * 512 + tid] = g1[i * 512 + tid];
    const u32x4* g2 = reinterpret_cast<const u32x4*>(b1F + (size_t)bh * 8 * 5 * 64 * 8);
    u32x4* s2 = reinterpret_cast<u32x4*>(b1_lds);
#pragma unroll
    for (int i = 0; i < 5; ++i) s2[i * 512 + tid] = g2[i * 512 + tid];
  }
  // xq frags from global (once per wave)
  const unsigned short* xqb = Xq + ((size_t)h * NTOK + b * LLEN) * KX;
  s16x8 xq[2][3];
#pragma unroll
  for (int qt = 0; qt < 2; ++qt)
#pragma unroll
    for (int xs = 0; xs < 3; ++xs)
      xq[qt][xs] = *reinterpret_cast<const s16x8*>(
          xqb + (size_t)(qb + 16 * qt + l15) * KX + 32 * xs + 8 * l4);
  __syncthreads();

  f32x4 acc3[2][5] = {};
#pragma unroll
  for (int ks = 0; ks < 8; ++ks) {
    f32x4 a0 = {}, b0 = {}, a1 = {}, b1 = {};
#pragma unroll
    for (int xs = 0; xs < 3; ++xs) {
      s16x8 p0 = *reinterpret_cast<const s16x8*>(pf_lds + (((2 * ks) * 3 + xs) * 64 + l) * 8);
      s16x8 p1 = *reinterpret_cast<const s16x8*>(pf_lds + (((2 * ks + 1) * 3 + xs) * 64 + l) * 8);
      a0 = MFMA16(p0, xq[0][xs], a0);
      b0 = MFMA16(p1, xq[0][xs], b0);
      a1 = MFMA16(p0, xq[1][xs], a1);
      b1 = MFMA16(p1, xq[1][xs], b1);
    }
    s16x8 pa0, pa1;
#pragma unroll
    for (int r = 0; r < 4; ++r) {
      pa0[r]     = (short)f2bf(__expf(a0[r]));
      pa0[4 + r] = (short)f2bf(__expf(b0[r]));
      pa1[r]     = (short)f2bf(__expf(a1[r]));
      pa1[4 + r] = (short)f2bf(__expf(b1[r]));
    }
#pragma unroll
    for (int ne = 0; ne < 5; ++ne) {
      s16x8 vb = *reinterpret_cast<const s16x8*>(b1_lds + ((ks * 5 + ne) * 64 + l) * 8);
      acc3[0][ne] = MFMA16(pa0, vb, acc3[0][ne]);
      acc3[1][ne] = MFMA16(pa1, vb, acc3[1][ne]);
    }
  }
#pragma unroll
  for (int qt = 0; qt < 2; ++qt) {
    float inv[4];
#pragma unroll
    for (int r = 0; r < 4; ++r) {
      float den = __shfl(acc3[qt][4][r], 16 * l4, 64);   // e=64 lives in lanes l15==0
      den = den < EPSV ? EPSV : den;
      inv[r] = 1.0f / den;
    }
#pragma unroll
    for (int ne = 0; ne < 4; ++ne)
#pragma unroll
      for (int r = 0; r < 4; ++r)
        out[((size_t)(b * LLEN + qb + 16 * qt + 4 * l4 + r) * HH + h) * 64 + l15 + 16 * ne] =
            acc3[qt][ne][r] * inv[r];
  }
}

// ---------------------------------------------------------------------------
extern "C" void kernel_launch(void* const* d_in, const int* in_sizes, int n_in,
                              void* d_out, int out_size, void* d_ws, size_t ws_size,
                              hipStream_t stream) {
  const float* qs   = (const float*)d_in[0];
  const float* ks   = (const float*)d_in[1];
  const float* vs   = (const float*)d_in[2];
  const float* qs_s = (const float*)d_in[3];
  const float* ks_s = (const float*)d_in[4];
  const float* W    = (const float*)d_in[5];
  const float* proj = (const float*)d_in[6];
  const float* a    = (const float*)d_in[7];
  float* out = (float*)d_out;

  char* ws = (char*)d_ws;
  unsigned short* projF = (unsigned short*)(ws + OFF_PROJF);
  unsigned short* Xq    = (unsigned short*)(ws + OFF_XQ);
  unsigned short* Xk    = (unsigned short*)(ws + OFF_XK);
  float*          hkp   = (float*)(ws + OFF_HK);
  unsigned short* vF    = (unsigned short*)(ws + OFF_VF);
  float*          parts = (float*)(ws + OFF_PARTS);
  unsigned short* b1F   = (unsigned short*)(ws + OFF_B1F);

  prep_projF<<<1, 256, 0, stream>>>(proj, projF);
  prep_x<<<PX_BLOCKS, 256, 0, stream>>>(qs, ks, qs_s, ks_s, W, a, Xq, Xk, hkp);
  prep_vF<<<dim3(64, 32), 256, 0, stream>>>(vs, vF);
  f1_k<<<dim3(32, 16), 512, 0, stream>>>(Xk, projF, vF, hkp, parts);
  reduce_t<<<dim3(32, 4), 256, 0, stream>>>(parts, b1F);
  f2_k<<<dim3(32, 16), 512, 0, stream>>>(Xq, projF, b1F, out);
}

// Round 7
// 106.816 us; speedup vs baseline: 1.5468x; 1.0663x over previous
//
#include <hip/hip_runtime.h>
#include <hip/hip_bf16.h>
#include <math.h>

// Problem dims (fixed by setup_inputs)
#define BB 4
#define LLEN 4096
#define HH 8
#define MM 256
#define KX 96          // padded x-dim: 64 qk + 8 fourier + [72]=hq(-1 col) + zeros
#define EE 80          // padded c-dim: 64 v + 1 ones + 15 zero
#define NTOK 16384     // BB*LLEN
#define NORM 0.35355339059327373f   // 64^-0.25 (folded into projF cols 0..63)
#define NORM2 0.125f                // NORM^2
#define LN16 2.7725887222397811f    // ln(sqrt(256)) folded into h => exp includes 1/sqrt(m)
#define EPSV 1e-6f
#define TWO_PI_F 6.283185307179586f
#define PX_BLOCKS 2048

typedef __attribute__((ext_vector_type(8))) short s16x8;   // 8 bf16 (4 VGPRs)
typedef __attribute__((ext_vector_type(4))) short s16x4;   // 4 bf16
typedef __attribute__((ext_vector_type(2))) short s16x2;
typedef __attribute__((ext_vector_type(4))) float f32x4;   // MFMA acc
typedef __attribute__((ext_vector_type(4))) unsigned int u32x4;

#define MFMA16(A,B,C) __builtin_amdgcn_mfma_f32_16x16x32_bf16(A,B,C,0,0,0)

static __device__ __forceinline__ unsigned short f2bf(float f) {
  union { float f; unsigned int u; } v; v.f = f;
  unsigned int r = v.u + 0x7FFFu + ((v.u >> 16) & 1u);   // round-to-nearest-even
  return (unsigned short)(r >> 16);
}

// ---- workspace byte offsets (total ~116 MB) ----
#define OFF_PROJF 0u
#define OFF_XQ    49152u
#define OFF_XK    (OFF_XQ + 25165824u)
#define OFF_HQ    (OFF_XK + 25165824u)   // unused slot
#define OFF_HK    (OFF_HQ + 524288u)
#define OFF_VF    (OFF_HK + 524288u)     // 20971520 B
#define OFF_PARTS (OFF_VF + 20971520u)   // 41943040 B
#define OFF_B1F   (OFF_PARTS + 41943040u) // 1310720 B

// ---------------------------------------------------------------------------
// projF fragment-major: chunk c = mt*3+xs (48 chunks), lane l, j=0..7:
//   value = projLogical[(l&15)+16*mt][32*xs+8*(l>>4)+j]
// projLogical[m][d] = d<64: proj[m][d]*NORM; d<72: proj[m][d]; d==72: -1; else 0
// ---------------------------------------------------------------------------
__global__ __launch_bounds__(256) void prep_projF(const float* __restrict__ proj,
                                                  unsigned short* __restrict__ projF) {
  int t = threadIdx.x;
  int l = t & 63, grp = t >> 6;
  int l15 = l & 15, l4 = l >> 4;
  for (int c = grp; c < 48; c += 4) {
    int mt = c / 3, xs = c % 3;
    int m = l15 + 16 * mt;
    s16x8 o;
#pragma unroll
    for (int j = 0; j < 8; ++j) {
      int d = 32 * xs + 8 * l4 + j;
      unsigned short u;
      if (d < 64)      u = f2bf(proj[m * 72 + d] * NORM);
      else if (d < 72) u = f2bf(proj[m * 72 + d]);
      else if (d == 72) u = 0xBF80;  // bf16(-1): pairs with Xq col72 = hq
      else             u = 0;
      o[j] = (short)u;
    }
    *reinterpret_cast<s16x8*>(projF + ((size_t)c * 64 + l) * 8) = o;
  }
}

// ---------------------------------------------------------------------------
// prep_x (proven): X layout [h][token][96] bf16; q col72 = hq, k col72 = 0;
// hkp[h][token] f32.
// ---------------------------------------------------------------------------
__global__ __launch_bounds__(256) void prep_x(
    const float* __restrict__ qs, const float* __restrict__ ks,
    const float* __restrict__ qs_s, const float* __restrict__ ks_s,
    const float* __restrict__ W, const float* __restrict__ a,
    unsigned short* __restrict__ Xq, unsigned short* __restrict__ Xk,
    float* __restrict__ hkp) {
  const int NW_TOT = PX_BLOCKS * 4;
  int wid = blockIdx.x * 4 + (threadIdx.x >> 6);
  int l = threadIdx.x & 63;
  int l15 = l & 15, g = l >> 4;

  for (int qd = wid; qd < 65536; qd += NW_TOT) {
    int row = qd * 4 + g;
    bool isq = row < 131072;
    int t = isq ? row : row - 131072;
    int token = t >> 3, h = t & 7;
    const float* src = (isq ? qs : ks) + (size_t)t * 64;
    unsigned short* dst = (isq ? Xq : Xk) + ((size_t)h * NTOK + token) * KX;

    f32x4 v = *reinterpret_cast<const f32x4*>(src + 4 * l15);
    float ss = v[0] * v[0] + v[1] * v[1] + v[2] * v[2] + v[3] * v[3];
    s16x4 o;
#pragma unroll
    for (int i = 0; i < 4; ++i) o[i] = (short)f2bf(v[i]);
    *reinterpret_cast<s16x4*>(dst + 4 * l15) = o;

    float contrib = ss * NORM2;
    if (l15 < 8) {
      float sv = (isq ? qs_s : ks_s)[token] * TWO_PI_F;
      int dim = 8 * h + l15;
      float ph = sv * W[dim & 31];
      float e = (dim < 32) ? sinf(ph) : cosf(ph);
      if (isq) e *= a[h];
      contrib += e * e;
      dst[64 + l15] = f2bf(e);
    }
    if (l15 > 0 && l15 < 12) {
      s16x2 z = {};
      *reinterpret_cast<s16x2*>(dst + 72 + 2 * l15) = z;
    }
#pragma unroll
    for (int m = 1; m < 16; m <<= 1) contrib += __shfl_xor(contrib, m, 64);
    if (l15 == 0) {
      float hval = 0.5f * contrib + LN16;
      s16x2 hz;
      hz[0] = isq ? (short)f2bf(hval) : (short)0;
      hz[1] = 0;
      *reinterpret_cast<s16x2*>(dst + 72) = hz;
      if (!isq) hkp[h * NTOK + token] = hval;
    }
  }
}

// ---------------------------------------------------------------------------
// vF fragment-major: [bh][kslot(128)][ne(5)][lane][8]:
//   value = c[e=(l&15)+16ne][k = 32*kslot + 16*(j>>2) + 4*(l>>4) + (j&3)]
// ---------------------------------------------------------------------------
__global__ __launch_bounds__(256) void prep_vF(const float* __restrict__ vs,
                                               unsigned short* __restrict__ vF) {
  int kc = blockIdx.x;   // 0..63 (64-key chunk)
  int bh = blockIdx.y;   // 0..31
  int b = bh >> 3, h = bh & 7;
  int t = threadIdx.x;
  __shared__ unsigned short tile[64][72];
  int k = t >> 2, seg = t & 3;
  const f32x4* src = reinterpret_cast<const f32x4*>(
      vs + (((size_t)(b * LLEN + kc * 64 + k)) * HH + h) * 64 + seg * 16);
#pragma unroll
  for (int j = 0; j < 4; ++j) {
    f32x4 v = src[j];
#pragma unroll
    for (int i = 0; i < 4; ++i) tile[k][seg * 16 + j * 4 + i] = f2bf(v[i]);
  }
  __syncthreads();
  int l = t & 63, ks2 = (t >> 6) & 1, rep = t >> 7;
  int l15 = l & 15, l4 = l >> 4;
  int nelo = rep ? 3 : 0, nehi = rep ? 5 : 3;
  for (int ne = nelo; ne < nehi; ++ne) {
    int e = l15 + 16 * ne;
    s16x8 o;
#pragma unroll
    for (int j = 0; j < 8; ++j) {
      int kl = 32 * ks2 + 16 * (j >> 2) + 4 * l4 + (j & 3);
      unsigned short u;
      if (e < 64)       u = tile[kl][e];
      else if (e == 64) u = 0x3F80;  // bf16(1.0)
      else              u = 0;
      o[j] = (short)u;
    }
    size_t kslot = (size_t)kc * 2 + ks2;
    *reinterpret_cast<s16x8*>(
        vF + (((size_t)bh * 128 + kslot) * 5 + ne) * 64 * 8 + (size_t)l * 8) = o;
  }
}

// ---------------------------------------------------------------------------
// F1: fused phi_k GEMM + exp + buf1 GEMM. 512 threads (8 waves, 2 mt each).
// LDS: projF 48K monolithic + double-buffered per-iter {Xk tile 8K swizzled,
// vF kslot 5K} = 74 KB -> 2 blocks/CU. 1 barrier/iter.
// ---------------------------------------------------------------------------
__global__ __launch_bounds__(512, 2) void f1_k(
    const unsigned short* __restrict__ Xk, const unsigned short* __restrict__ projF,
    const unsigned short* __restrict__ vF, const float* __restrict__ hkp,
    float* __restrict__ parts) {
  __shared__ unsigned short pf_lds[24576];       // 48 KB
  __shared__ unsigned char  sbuf[2][13312];      // [0..8191]=Xk tile, [8192..]=vF kslot

  int bh = blockIdx.x, split = blockIdx.y;
  int b = bh >> 3, h = bh & 7;
  int tid = threadIdx.x;
  int w = tid >> 6, l = tid & 63;
  int l15 = l & 15, l4 = l >> 4;
  int kbase = split * 256;

  const unsigned short* xkb = Xk + ((size_t)h * NTOK + b * LLEN) * KX;
  const float* hkb = hkp + h * NTOK + b * LLEN;
  const unsigned short* vfb = vF + ((size_t)bh * 128 + split * 8) * 5 * 64 * 8;

  int xrow = tid / 12;
  int xcol = tid * 16 - xrow * 192;
  int xoff = xrow * 256 + (xcol ^ ((xrow & 7) << 4));

  // ---- stage projF + tile 0 ----
  {
    const u32x4* g1 = reinterpret_cast<const u32x4*>(projF);
    u32x4* s1 = reinterpret_cast<u32x4*>(pf_lds);
#pragma unroll
    for (int i = 0; i < 6; ++i) s1[i * 512 + tid] = g1[i * 512 + tid];
    if (tid < 384) {
      u32x4 x0 = reinterpret_cast<const u32x4*>(xkb + (size_t)kbase * KX)[tid];
      *reinterpret_cast<u32x4*>(&sbuf[0][xoff]) = x0;
    }
    if (tid < 320) {
      u32x4 v0 = reinterpret_cast<const u32x4*>(vfb)[tid];
      *reinterpret_cast<u32x4*>(&sbuf[0][8192 + tid * 16]) = v0;
    }
  }
  __syncthreads();

  f32x4 acc2[2][5] = {};

  for (int it = 0; it < 8; ++it) {
    int k0 = kbase + it * 32;
    int cur = it & 1, nxt = cur ^ 1;
    // prefetch next tile (issue early, write late)
    u32x4 nx, nv;
    if (it < 7) {
      if (tid < 384)
        nx = reinterpret_cast<const u32x4*>(xkb + (size_t)(k0 + 32) * KX)[tid];
      if (tid < 320)
        nv = reinterpret_cast<const u32x4*>(vfb + (size_t)(it + 1) * 2560)[tid];
    }
    f32x4 hk0 = *reinterpret_cast<const f32x4*>(hkb + k0 + 4 * l4);
    f32x4 hk1 = *reinterpret_cast<const f32x4*>(hkb + k0 + 16 + 4 * l4);

    // ---- GEMM1: P = Xk . projF^T ----
    s16x8 ak0[3], ak1[3], pf0[3], pf1[3];
#pragma unroll
    for (int xs = 0; xs < 3; ++xs) {
      int co = (64 * xs + 16 * l4) ^ ((l15 & 7) << 4);
      ak0[xs] = *reinterpret_cast<const s16x8*>(&sbuf[cur][l15 * 256 + co]);
      ak1[xs] = *reinterpret_cast<const s16x8*>(&sbuf[cur][(16 + l15) * 256 + co]);
      pf0[xs] = *reinterpret_cast<const s16x8*>(pf_lds + (((2 * w) * 3 + xs) * 64 + l) * 8);
      pf1[xs] = *reinterpret_cast<const s16x8*>(pf_lds + (((2 * w + 1) * 3 + xs) * 64 + l) * 8);
    }
    f32x4 acc1[2][2] = {};
#pragma unroll
    for (int xs = 0; xs < 3; ++xs) {
      acc1[0][0] = MFMA16(ak0[xs], pf0[xs], acc1[0][0]);
      acc1[0][1] = MFMA16(ak0[xs], pf1[xs], acc1[0][1]);
      acc1[1][0] = MFMA16(ak1[xs], pf0[xs], acc1[1][0]);
      acc1[1][1] = MFMA16(ak1[xs], pf1[xs], acc1[1][1]);
    }
    // ---- exp -> bf16 A-frag (k-perm: slot(l4,j) <-> key 16(j>>2)+4l4+(j&3)) ----
    s16x8 pa[2];
#pragma unroll
    for (int nt = 0; nt < 2; ++nt)
#pragma unroll
      for (int r = 0; r < 4; ++r) {
        pa[nt][r]     = (short)f2bf(__expf(acc1[0][nt][r] - hk0[r]));
        pa[nt][4 + r] = (short)f2bf(__expf(acc1[1][nt][r] - hk1[r]));
      }
    // ---- GEMM2: acc2 += P^T . c ----
#pragma unroll
    for (int ne = 0; ne < 5; ++ne) {
      s16x8 vb = *reinterpret_cast<const s16x8*>(&sbuf[cur][8192 + (ne * 64 + l) * 16]);
      acc2[0][ne] = MFMA16(pa[0], vb, acc2[0][ne]);
      acc2[1][ne] = MFMA16(pa[1], vb, acc2[1][ne]);
    }
    // ---- write next tile, barrier ----
    if (it < 7) {
      if (tid < 384) *reinterpret_cast<u32x4*>(&sbuf[nxt][xoff]) = nx;
      if (tid < 320) *reinterpret_cast<u32x4*>(&sbuf[nxt][8192 + tid * 16]) = nv;
    }
    __syncthreads();
  }

#pragma unroll
  for (int nt = 0; nt < 2; ++nt)
#pragma unroll
    for (int ne = 0; ne < 5; ++ne)
#pragma unroll
      for (int r = 0; r < 4; ++r) {
        int m = 16 * (2 * w + nt) + 4 * l4 + r;
        parts[(((size_t)split * 32 + bh) * MM + m) * EE + l15 + 16 * ne] = acc2[nt][ne][r];
      }
}

// ---------------------------------------------------------------------------
// reduce 16 splits -> b1F fragment-major [bh][ks(8)][ne(5)][lane][8] bf16
// ---------------------------------------------------------------------------
__global__ __launch_bounds__(256) void reduce_t(const float* __restrict__ parts,
                                                unsigned short* __restrict__ b1F) {
  int bh = blockIdx.x;   // 32
  int mc = blockIdx.y;   // 4 (64 m each)
  __shared__ float s[64 * 80];
  size_t base = ((size_t)bh * MM + mc * 64) * EE;
  for (int o = threadIdx.x; o < 64 * 80; o += 256) {
    float sum = 0.f;
#pragma unroll
    for (int sp = 0; sp < 16; ++sp)
      sum += parts[(size_t)sp * 32 * MM * EE + base + o];
    s[o] = sum;
  }
  __syncthreads();
  int t = threadIdx.x, l = t & 63, kl = (t >> 6) & 1, rep = t >> 7;
  int l15 = l & 15, l4 = l >> 4;
  int nelo = rep ? 3 : 0, nehi = rep ? 5 : 3;
  for (int ne = nelo; ne < nehi; ++ne) {
    s16x8 o;
#pragma unroll
    for (int j = 0; j < 8; ++j) {
      int ml = 32 * kl + 16 * (j >> 2) + 4 * l4 + (j & 3);
      o[j] = (short)f2bf(s[ml * 80 + l15 + 16 * ne]);
    }
    int ks = mc * 2 + kl;
    *reinterpret_cast<s16x8*>(
        b1F + (((size_t)bh * 8 + ks) * 5 + ne) * 64 * 8 + (size_t)l * 8) = o;
  }
}

// ---------------------------------------------------------------------------
// F2: fused phi_q GEMM + exp + output GEMM. 512 threads (8 waves x 32 q).
// Both inner operands streamed per-iter through a 2x11264B double buffer:
// {projF chunk-pair 6144B, b1F ks-slice 5120B}. LDS 22.5 KB total.
// ---------------------------------------------------------------------------
__global__ __launch_bounds__(512, 2) void f2_k(
    const unsigned short* __restrict__ Xq, const unsigned short* __restrict__ projF,
    const unsigned short* __restrict__ b1F, float* __restrict__ out) {
  __shared__ unsigned char sbuf[2][11264];   // [0..6143]=pf pair, [6144..]=b1 slice

  int bh = blockIdx.x, qc = blockIdx.y;
  int b = bh >> 3, h = bh & 7;
  int tid = threadIdx.x;
  int w = tid >> 6, l = tid & 63;
  int l15 = l & 15, l4 = l >> 4;
  int qb = qc * 256 + w * 32;
  const unsigned short* b1b = b1F + (size_t)bh * 8 * 5 * 64 * 8;

  // xq frags from global (once per wave)
  const unsigned short* xqb = Xq + ((size_t)h * NTOK + b * LLEN) * KX;
  s16x8 xq[2][3];
#pragma unroll
  for (int qt = 0; qt < 2; ++qt)
#pragma unroll
    for (int xs = 0; xs < 3; ++xs)
      xq[qt][xs] = *reinterpret_cast<const s16x8*>(
          xqb + (size_t)(qb + 16 * qt + l15) * KX + 32 * xs + 8 * l4);

  // stage iter 0
  if (tid < 384)
    *reinterpret_cast<u32x4*>(&sbuf[0][tid * 16]) =
        reinterpret_cast<const u32x4*>(projF)[tid];
  if (tid < 320)
    *reinterpret_cast<u32x4*>(&sbuf[0][6144 + tid * 16]) =
        reinterpret_cast<const u32x4*>(b1b)[tid];
  __syncthreads();

  f32x4 acc3[2][5] = {};
#pragma unroll
  for (int ks = 0; ks < 8; ++ks) {
    int cur = ks & 1, nxt = cur ^ 1;
    u32x4 npf, nb1;
    if (ks < 7) {
      if (tid < 384)
        npf = reinterpret_cast<const u32x4*>(projF + (size_t)(2 * ks + 2) * 3 * 512)[tid];
      if (tid < 320)
        nb1 = reinterpret_cast<const u32x4*>(b1b + (size_t)(ks + 1) * 2560)[tid];
    }
    f32x4 a0 = {}, b0 = {}, a1 = {}, b1 = {};
#pragma unroll
    for (int xs = 0; xs < 3; ++xs) {
      s16x8 p0 = *reinterpret_cast<const s16x8*>(&sbuf[cur][(xs * 64 + l) * 16]);
      s16x8 p1 = *reinterpret_cast<const s16x8*>(&sbuf[cur][3072 + (xs * 64 + l) * 16]);
      a0 = MFMA16(p0, xq[0][xs], a0);
      b0 = MFMA16(p1, xq[0][xs], b0);
      a1 = MFMA16(p0, xq[1][xs], a1);
      b1 = MFMA16(p1, xq[1][xs], b1);
    }
    s16x8 pa0, pa1;
#pragma unroll
    for (int r = 0; r < 4; ++r) {
      pa0[r]     = (short)f2bf(__expf(a0[r]));
      pa0[4 + r] = (short)f2bf(__expf(b0[r]));
      pa1[r]     = (short)f2bf(__expf(a1[r]));
      pa1[4 + r] = (short)f2bf(__expf(b1[r]));
    }
#pragma unroll
    for (int ne = 0; ne < 5; ++ne) {
      s16x8 vb = *reinterpret_cast<const s16x8*>(&sbuf[cur][6144 + (ne * 64 + l) * 16]);
      acc3[0][ne] = MFMA16(pa0, vb, acc3[0][ne]);
      acc3[1][ne] = MFMA16(pa1, vb, acc3[1][ne]);
    }
    if (ks < 7) {
      if (tid < 384) *reinterpret_cast<u32x4*>(&sbuf[nxt][tid * 16]) = npf;
      if (tid < 320) *reinterpret_cast<u32x4*>(&sbuf[nxt][6144 + tid * 16]) = nb1;
    }
    __syncthreads();
  }
#pragma unroll
  for (int qt = 0; qt < 2; ++qt) {
    float inv[4];
#pragma unroll
    for (int r = 0; r < 4; ++r) {
      float den = __shfl(acc3[qt][4][r], 16 * l4, 64);   // e=64 lives in lanes l15==0
      den = den < EPSV ? EPSV : den;
      inv[r] = 1.0f / den;
    }
#pragma unroll
    for (int ne = 0; ne < 4; ++ne)
#pragma unroll
      for (int r = 0; r < 4; ++r)
        out[((size_t)(b * LLEN + qb + 16 * qt + 4 * l4 + r) * HH + h) * 64 + l15 + 16 * ne] =
            acc3[qt][ne][r] * inv[r];
  }
}

// ---------------------------------------------------------------------------
extern "C" void kernel_launch(void* const* d_in, const int* in_sizes, int n_in,
                              void* d_out, int out_size, void* d_ws, size_t ws_size,
                              hipStream_t stream) {
  const float* qs   = (const float*)d_in[0];
  const float* ks   = (const float*)d_in[1];
  const float* vs   = (const float*)d_in[2];
  const float* qs_s = (const float*)d_in[3];
  const float* ks_s = (const float*)d_in[4];
  const float* W    = (const float*)d_in[5];
  const float* proj = (const float*)d_in[6];
  const float* a    = (const float*)d_in[7];
  float* out = (float*)d_out;

  char* ws = (char*)d_ws;
  unsigned short* projF = (unsigned short*)(ws + OFF_PROJF);
  unsigned short* Xq    = (unsigned short*)(ws + OFF_XQ);
  unsigned short* Xk    = (unsigned short*)(ws + OFF_XK);
  float*          hkp   = (float*)(ws + OFF_HK);
  unsigned short* vF    = (unsigned short*)(ws + OFF_VF);
  float*          parts = (float*)(ws + OFF_PARTS);
  unsigned short* b1F   = (unsigned short*)(ws + OFF_B1F);

  prep_projF<<<1, 256, 0, stream>>>(proj, projF);
  prep_x<<<PX_BLOCKS, 256, 0, stream>>>(qs, ks, qs_s, ks_s, W, a, Xq, Xk, hkp);
  prep_vF<<<dim3(64, 32), 256, 0, stream>>>(vs, vF);
  f1_k<<<dim3(32, 16), 512, 0, stream>>>(Xk, projF, vF, hkp, parts);
  reduce_t<<<dim3(32, 4), 256, 0, stream>>>(parts, b1F);
  f2_k<<<dim3(32, 16), 512, 0, stream>>>(Xq, projF, b1F, out);
}

// Round 8
// 93.267 us; speedup vs baseline: 1.7715x; 1.1453x over previous
//
#include <hip/hip_runtime.h>
#include <hip/hip_bf16.h>
#include <math.h>

// Problem dims (fixed by setup_inputs)
#define BB 4
#define LLEN 4096
#define HH 8
#define MM 256
#define KX 96          // padded x-dim: 64 qk + 8 fourier + [72]=hq(-1 col) + zeros
#define EE 80          // padded c-dim: 64 v + 1 ones + 15 zero
#define NTOK 16384     // BB*LLEN
#define NORM 0.35355339059327373f   // 64^-0.25 (folded into projF cols 0..63)
#define NORM2 0.125f                // NORM^2
#define LN16 2.7725887222397811f    // ln(sqrt(256)) folded into h => exp includes 1/sqrt(m)
#define EPSV 1e-6f
#define TWO_PI_F 6.283185307179586f

typedef __attribute__((ext_vector_type(8))) short s16x8;   // 8 bf16 (4 VGPRs)
typedef __attribute__((ext_vector_type(4))) short s16x4;   // 4 bf16
typedef __attribute__((ext_vector_type(4))) float f32x4;   // MFMA acc
typedef __attribute__((ext_vector_type(4))) unsigned int u32x4;

#define MFMA16(A,B,C) __builtin_amdgcn_mfma_f32_16x16x32_bf16(A,B,C,0,0,0)

static __device__ __forceinline__ unsigned short f2bf(float f) {
  union { float f; unsigned int u; } v; v.f = f;
  unsigned int r = v.u + 0x7FFFu + ((v.u >> 16) & 1u);   // round-to-nearest-even
  return (unsigned short)(r >> 16);
}

// ---- workspace byte offsets ----
#define OFF_PROJF 0u
#define OFF_VF    524288u                 // 20971520 B
#define OFF_PARTS (OFF_VF + 20971520u)    // 41943040 B
#define OFF_B1F   (OFF_PARTS + 41943040u) // 1310720 B

// ---------------------------------------------------------------------------
// prep_vF (+ projF build in the extra kc==64 block).
// vF fragment-major: [bh][kslot(128)][ne(5)][lane][8]:
//   value = c[e=(l&15)+16ne][k = 32*kslot + 16*(j>>2) + 4*(l>>4) + (j&3)]
// projF fragment-major: chunk c = mt*3+xs, lane l, j:
//   projLogical[(l&15)+16mt][32xs+8(l>>4)+j]; cols: 0..63 proj*NORM,
//   64..71 proj, 72 = -1 (hq fold), 73..95 = 0.
// ---------------------------------------------------------------------------
__global__ __launch_bounds__(256) void prep_vF(const float* __restrict__ vs,
                                               const float* __restrict__ proj,
                                               unsigned short* __restrict__ vF,
                                               unsigned short* __restrict__ projF) {
  int kc = blockIdx.x;   // 0..63 vF chunks; 64 = projF block
  int bh = blockIdx.y;   // 0..31
  if (kc == 64) {
    if (bh != 0) return;
    int t = threadIdx.x;
    int l = t & 63, grp = t >> 6;
    int l15 = l & 15, l4 = l >> 4;
    for (int c = grp; c < 48; c += 4) {
      int mt = c / 3, xs = c % 3;
      int m = l15 + 16 * mt;
      s16x8 o;
#pragma unroll
      for (int j = 0; j < 8; ++j) {
        int d = 32 * xs + 8 * l4 + j;
        unsigned short u;
        if (d < 64)       u = f2bf(proj[m * 72 + d] * NORM);
        else if (d < 72)  u = f2bf(proj[m * 72 + d]);
        else if (d == 72) u = 0xBF80;  // bf16(-1)
        else              u = 0;
        o[j] = (short)u;
      }
      *reinterpret_cast<s16x8*>(projF + ((size_t)c * 64 + l) * 8) = o;
    }
    return;
  }
  int b = bh >> 3, h = bh & 7;
  int t = threadIdx.x;
  __shared__ unsigned short tile[64][72];
  int k = t >> 2, seg = t & 3;
  const f32x4* src = reinterpret_cast<const f32x4*>(
      vs + (((size_t)(b * LLEN + kc * 64 + k)) * HH + h) * 64 + seg * 16);
#pragma unroll
  for (int j = 0; j < 4; ++j) {
    f32x4 v = src[j];
#pragma unroll
    for (int i = 0; i < 4; ++i) tile[k][seg * 16 + j * 4 + i] = f2bf(v[i]);
  }
  __syncthreads();
  int l = t & 63, ks2 = (t >> 6) & 1, rep = t >> 7;
  int l15 = l & 15, l4 = l >> 4;
  int nelo = rep ? 3 : 0, nehi = rep ? 5 : 3;
  for (int ne = nelo; ne < nehi; ++ne) {
    int e = l15 + 16 * ne;
    s16x8 o;
#pragma unroll
    for (int j = 0; j < 8; ++j) {
      int kl = 32 * ks2 + 16 * (j >> 2) + 4 * l4 + (j & 3);
      unsigned short u;
      if (e < 64)       u = tile[kl][e];
      else if (e == 64) u = 0x3F80;  // bf16(1.0)
      else              u = 0;
      o[j] = (short)u;
    }
    size_t kslot = (size_t)kc * 2 + ks2;
    *reinterpret_cast<s16x8*>(
        vF + (((size_t)bh * 128 + kslot) * 5 + ne) * 64 * 8 + (size_t)l * 8) = o;
  }
}

// ---------------------------------------------------------------------------
// F1: fused {ks f32->bf16 + fourier + hk} staging + phi_k GEMM + exp + buf1
// GEMM. 512 threads (8 waves, 2 mt each). LDS: projF 48K + dbuf {ks tile 8K
// swizzled, vF kslot 5K} + hk 2x32 f32. Direct ks reads — no Xk buffer.
// ---------------------------------------------------------------------------
__global__ __launch_bounds__(512, 2) void f1_k(
    const float* __restrict__ ks, const float* __restrict__ ks_s,
    const float* __restrict__ W,
    const unsigned short* __restrict__ projF,
    const unsigned short* __restrict__ vF,
    float* __restrict__ parts) {
  __shared__ unsigned short pf_lds[24576];       // 48 KB
  __shared__ unsigned char  sbuf[2][13312];      // [0..8191]=ks tile, [8192..]=vF kslot
  __shared__ alignas(16) float hk_sh[2][32];

  int bh = blockIdx.x, split = blockIdx.y;
  int b = bh >> 3, h = bh & 7;
  int tid = threadIdx.x;
  int w = tid >> 6, l = tid & 63;
  int l15 = l & 15, l4 = l >> 4;
  int kbase = split * 256;
  int row = tid >> 4, seg = tid & 15;
  int s4 = (row & 7) << 4;

  const float* ksb = ks + ((size_t)(b * LLEN + kbase) * HH + h) * 64;  // row stride 512 f32
  const float* kss = ks_s + (size_t)b * LLEN + kbase;
  const unsigned short* vfb = vF + ((size_t)bh * 128 + split * 8) * 5 * 64 * 8;

  // per-thread fourier constants (seg<8 threads own fourier element seg)
  float wv = 0.f; bool issin = false;
  if (seg < 8) { int dim = 8 * h + seg; wv = W[dim & 31] * TWO_PI_F; issin = dim < 32; }

  // ---- prologue: zero upper 128B of every row (both bufs) + stage projF ----
  {
    int bi = tid >> 8, rem = tid & 255;
    u32x4 z = {};
    *reinterpret_cast<u32x4*>(&sbuf[bi][(rem >> 3) * 256 + 128 + (rem & 7) * 16]) = z;
    const u32x4* g1 = reinterpret_cast<const u32x4*>(projF);
    u32x4* s1 = reinterpret_cast<u32x4*>(pf_lds);
#pragma unroll
    for (int i = 0; i < 6; ++i) s1[i * 512 + tid] = g1[i * 512 + tid];
  }
  __syncthreads();
  // ---- stage tile 0 + vF slice 0 ----
  {
    f32x4 kv = *reinterpret_cast<const f32x4*>(ksb + (size_t)row * 512 + 4 * seg);
    float part = (kv[0]*kv[0] + kv[1]*kv[1] + kv[2]*kv[2] + kv[3]*kv[3]) * NORM2;
    s16x4 o;
#pragma unroll
    for (int i = 0; i < 4; ++i) o[i] = (short)f2bf(kv[i]);
    *reinterpret_cast<s16x4*>(&sbuf[0][row * 256 + ((8 * seg) ^ s4)]) = o;
    if (seg < 8) {
      float ph = kss[row] * wv;
      float e = issin ? sinf(ph) : cosf(ph);
      part += e * e;
      *reinterpret_cast<unsigned short*>(&sbuf[0][row * 256 + ((128 + 2 * seg) ^ s4)]) = f2bf(e);
    }
#pragma unroll
    for (int m = 1; m < 16; m <<= 1) part += __shfl_xor(part, m, 64);
    if (seg == 0) hk_sh[0][row] = 0.5f * part + LN16;
    if (tid < 320)
      *reinterpret_cast<u32x4*>(&sbuf[0][8192 + tid * 16]) =
          reinterpret_cast<const u32x4*>(vfb)[tid];
  }
  __syncthreads();

  f32x4 acc2[2][5] = {};

  for (int it = 0; it < 8; ++it) {
    int cur = it & 1, nxt = cur ^ 1;
    // issue-early: next tile global loads
    f32x4 kvn; float svn = 0.f; u32x4 nv;
    if (it < 7) {
      kvn = *reinterpret_cast<const f32x4*>(
          ksb + (size_t)(32 * (it + 1) + row) * 512 + 4 * seg);
      if (seg < 8) svn = kss[32 * (it + 1) + row];
      if (tid < 320)
        nv = reinterpret_cast<const u32x4*>(vfb + (size_t)(it + 1) * 2560)[tid];
    }

    // ---- GEMM1: P = Xk . projF^T ----
    s16x8 ak0[3], ak1[3], pf0[3], pf1[3];
#pragma unroll
    for (int xs = 0; xs < 3; ++xs) {
      int co = (64 * xs + 16 * l4) ^ ((l15 & 7) << 4);
      ak0[xs] = *reinterpret_cast<const s16x8*>(&sbuf[cur][l15 * 256 + co]);
      ak1[xs] = *reinterpret_cast<const s16x8*>(&sbuf[cur][(16 + l15) * 256 + co]);
      pf0[xs] = *reinterpret_cast<const s16x8*>(pf_lds + (((2 * w) * 3 + xs) * 64 + l) * 8);
      pf1[xs] = *reinterpret_cast<const s16x8*>(pf_lds + (((2 * w + 1) * 3 + xs) * 64 + l) * 8);
    }
    f32x4 acc1[2][2] = {};
#pragma unroll
    for (int xs = 0; xs < 3; ++xs) {
      acc1[0][0] = MFMA16(ak0[xs], pf0[xs], acc1[0][0]);
      acc1[0][1] = MFMA16(ak0[xs], pf1[xs], acc1[0][1]);
      acc1[1][0] = MFMA16(ak1[xs], pf0[xs], acc1[1][0]);
      acc1[1][1] = MFMA16(ak1[xs], pf1[xs], acc1[1][1]);
    }
    // ---- exp -> bf16 A-frag (k-perm: slot(l4,j) <-> key 16(j>>2)+4l4+(j&3)) ----
    f32x4 hk0 = *reinterpret_cast<const f32x4*>(&hk_sh[cur][4 * l4]);
    f32x4 hk1 = *reinterpret_cast<const f32x4*>(&hk_sh[cur][16 + 4 * l4]);
    s16x8 pa[2];
#pragma unroll
    for (int nt = 0; nt < 2; ++nt)
#pragma unroll
      for (int r = 0; r < 4; ++r) {
        pa[nt][r]     = (short)f2bf(__expf(acc1[0][nt][r] - hk0[r]));
        pa[nt][4 + r] = (short)f2bf(__expf(acc1[1][nt][r] - hk1[r]));
      }
    // ---- GEMM2: acc2 += P^T . c ----
#pragma unroll
    for (int ne = 0; ne < 5; ++ne) {
      s16x8 vb = *reinterpret_cast<const s16x8*>(&sbuf[cur][8192 + (ne * 64 + l) * 16]);
      acc2[0][ne] = MFMA16(pa[0], vb, acc2[0][ne]);
      acc2[1][ne] = MFMA16(pa[1], vb, acc2[1][ne]);
    }
    // ---- write-late: convert + fourier + hk for next tile ----
    if (it < 7) {
      float part = (kvn[0]*kvn[0] + kvn[1]*kvn[1] + kvn[2]*kvn[2] + kvn[3]*kvn[3]) * NORM2;
      s16x4 o;
#pragma unroll
      for (int i = 0; i < 4; ++i) o[i] = (short)f2bf(kvn[i]);
      *reinterpret_cast<s16x4*>(&sbuf[nxt][row * 256 + ((8 * seg) ^ s4)]) = o;
      if (seg < 8) {
        float ph = svn * wv;
        float e = issin ? sinf(ph) : cosf(ph);
        part += e * e;
        *reinterpret_cast<unsigned short*>(&sbuf[nxt][row * 256 + ((128 + 2 * seg) ^ s4)]) = f2bf(e);
      }
#pragma unroll
      for (int m = 1; m < 16; m <<= 1) part += __shfl_xor(part, m, 64);
      if (seg == 0) hk_sh[nxt][row] = 0.5f * part + LN16;
      if (tid < 320) *reinterpret_cast<u32x4*>(&sbuf[nxt][8192 + tid * 16]) = nv;
    }
    __syncthreads();
  }

#pragma unroll
  for (int nt = 0; nt < 2; ++nt)
#pragma unroll
    for (int ne = 0; ne < 5; ++ne)
#pragma unroll
      for (int r = 0; r < 4; ++r) {
        int m = 16 * (2 * w + nt) + 4 * l4 + r;
        parts[(((size_t)split * 32 + bh) * MM + m) * EE + l15 + 16 * ne] = acc2[nt][ne][r];
      }
}

// ---------------------------------------------------------------------------
// reduce 16 splits -> b1F fragment-major [bh][ks(8)][ne(5)][lane][8] bf16
// ---------------------------------------------------------------------------
__global__ __launch_bounds__(256) void reduce_t(const float* __restrict__ parts,
                                                unsigned short* __restrict__ b1F) {
  int bh = blockIdx.x;   // 32
  int mc = blockIdx.y;   // 4 (64 m each)
  __shared__ float s[64 * 80];
  size_t base = ((size_t)bh * MM + mc * 64) * EE;
  for (int o = threadIdx.x; o < 64 * 80; o += 256) {
    float sum = 0.f;
#pragma unroll
    for (int sp = 0; sp < 16; ++sp)
      sum += parts[(size_t)sp * 32 * MM * EE + base + o];
    s[o] = sum;
  }
  __syncthreads();
  int t = threadIdx.x, l = t & 63, kl = (t >> 6) & 1, rep = t >> 7;
  int l15 = l & 15, l4 = l >> 4;
  int nelo = rep ? 3 : 0, nehi = rep ? 5 : 3;
  for (int ne = nelo; ne < nehi; ++ne) {
    s16x8 o;
#pragma unroll
    for (int j = 0; j < 8; ++j) {
      int ml = 32 * kl + 16 * (j >> 2) + 4 * l4 + (j & 3);
      o[j] = (short)f2bf(s[ml * 80 + l15 + 16 * ne]);
    }
    int ks = mc * 2 + kl;
    *reinterpret_cast<s16x8*>(
        b1F + (((size_t)bh * 8 + ks) * 5 + ne) * 64 * 8 + (size_t)l * 8) = o;
  }
}

// ---------------------------------------------------------------------------
// F2: fused {qs f32->frag + fourier + hq} + phi_q GEMM + exp + output GEMM.
// 512 threads (8 waves x 32 q). Operands streamed per-iter through a
// 2x11264B double buffer. Direct qs reads — no Xq buffer.
// ---------------------------------------------------------------------------
__global__ __launch_bounds__(512, 2) void f2_k(
    const float* __restrict__ qs, const float* __restrict__ qs_s,
    const float* __restrict__ W, const float* __restrict__ a,
    const unsigned short* __restrict__ projF,
    const unsigned short* __restrict__ b1F, float* __restrict__ out) {
  __shared__ unsigned char sbuf[2][11264];   // [0..6143]=pf pair, [6144..]=b1 slice

  int bh = blockIdx.x, qc = blockIdx.y;
  int b = bh >> 3, h = bh & 7;
  int tid = threadIdx.x;
  int w = tid >> 6, l = tid & 63;
  int l15 = l & 15, l4 = l >> 4;
  int qb = qc * 256 + w * 32;
  const unsigned short* b1b = b1F + (size_t)bh * 8 * 5 * 64 * 8;
  float ah = a[h];

  // build xq frags + hq in registers, straight from qs f32
  s16x8 xq[2][3];
#pragma unroll
  for (int qt = 0; qt < 2; ++qt) {
    int qrow = qb + 16 * qt + l15;
    const float* qr = qs + ((size_t)(b * LLEN + qrow) * HH + h) * 64;
    float part = 0.f;
#pragma unroll
    for (int xs = 0; xs < 2; ++xs) {
      f32x4 u0 = *reinterpret_cast<const f32x4*>(qr + 32 * xs + 8 * l4);
      f32x4 u1 = *reinterpret_cast<const f32x4*>(qr + 32 * xs + 8 * l4 + 4);
      s16x8 fr;
#pragma unroll
      for (int i = 0; i < 4; ++i) {
        part += u0[i] * u0[i] + u1[i] * u1[i];
        fr[i] = (short)f2bf(u0[i]);
        fr[4 + i] = (short)f2bf(u1[i]);
      }
      xq[qt][xs] = fr;
    }
    part *= NORM2;
    s16x8 fx = {};
    if (l4 == 0) {
      float sv = qs_s[(size_t)b * LLEN + qrow] * TWO_PI_F;
#pragma unroll
      for (int j = 0; j < 8; ++j) {
        int dim = 8 * h + j;
        float ph = sv * W[dim & 31];
        float e = (dim < 32) ? sinf(ph) : cosf(ph);
        e *= ah;
        part += e * e;
        fx[j] = (short)f2bf(e);
      }
    }
    part += __shfl_xor(part, 16, 64);
    part += __shfl_xor(part, 32, 64);
    if (l4 == 1) fx[0] = (short)f2bf(0.5f * part + LN16);
    xq[qt][2] = fx;
  }

  // stage iter 0
  if (tid < 384)
    *reinterpret_cast<u32x4*>(&sbuf[0][tid * 16]) =
        reinterpret_cast<const u32x4*>(projF)[tid];
  if (tid < 320)
    *reinterpret_cast<u32x4*>(&sbuf[0][6144 + tid * 16]) =
        reinterpret_cast<const u32x4*>(b1b)[tid];
  __syncthreads();

  f32x4 acc3[2][5] = {};
#pragma unroll
  for (int ks = 0; ks < 8; ++ks) {
    int cur = ks & 1, nxt = cur ^ 1;
    u32x4 npf, nb1;
    if (ks < 7) {
      if (tid < 384)
        npf = reinterpret_cast<const u32x4*>(projF + (size_t)(2 * ks + 2) * 3 * 512)[tid];
      if (tid < 320)
        nb1 = reinterpret_cast<const u32x4*>(b1b + (size_t)(ks + 1) * 2560)[tid];
    }
    f32x4 a0 = {}, b0 = {}, a1 = {}, b1 = {};
#pragma unroll
    for (int xs = 0; xs < 3; ++xs) {
      s16x8 p0 = *reinterpret_cast<const s16x8*>(&sbuf[cur][(xs * 64 + l) * 16]);
      s16x8 p1 = *reinterpret_cast<const s16x8*>(&sbuf[cur][3072 + (xs * 64 + l) * 16]);
      a0 = MFMA16(p0, xq[0][xs], a0);
      b0 = MFMA16(p1, xq[0][xs], b0);
      a1 = MFMA16(p0, xq[1][xs], a1);
      b1 = MFMA16(p1, xq[1][xs], b1);
    }
    s16x8 pa0, pa1;
#pragma unroll
    for (int r = 0; r < 4; ++r) {
      pa0[r]     = (short)f2bf(__expf(a0[r]));
      pa0[4 + r] = (short)f2bf(__expf(b0[r]));
      pa1[r]     = (short)f2bf(__expf(a1[r]));
      pa1[4 + r] = (short)f2bf(__expf(b1[r]));
    }
#pragma unroll
    for (int ne = 0; ne < 5; ++ne) {
      s16x8 vb = *reinterpret_cast<const s16x8*>(&sbuf[cur][6144 + (ne * 64 + l) * 16]);
      acc3[0][ne] = MFMA16(pa0, vb, acc3[0][ne]);
      acc3[1][ne] = MFMA16(pa1, vb, acc3[1][ne]);
    }
    if (ks < 7) {
      if (tid < 384) *reinterpret_cast<u32x4*>(&sbuf[nxt][tid * 16]) = npf;
      if (tid < 320) *reinterpret_cast<u32x4*>(&sbuf[nxt][6144 + tid * 16]) = nb1;
    }
    __syncthreads();
  }
#pragma unroll
  for (int qt = 0; qt < 2; ++qt) {
    float inv[4];
#pragma unroll
    for (int r = 0; r < 4; ++r) {
      float den = __shfl(acc3[qt][4][r], 16 * l4, 64);   // e=64 lives in lanes l15==0
      den = den < EPSV ? EPSV : den;
      inv[r] = 1.0f / den;
    }
#pragma unroll
    for (int ne = 0; ne < 4; ++ne)
#pragma unroll
      for (int r = 0; r < 4; ++r)
        out[((size_t)(b * LLEN + qb + 16 * qt + 4 * l4 + r) * HH + h) * 64 + l15 + 16 * ne] =
            acc3[qt][ne][r] * inv[r];
  }
}

// ---------------------------------------------------------------------------
extern "C" void kernel_launch(void* const* d_in, const int* in_sizes, int n_in,
                              void* d_out, int out_size, void* d_ws, size_t ws_size,
                              hipStream_t stream) {
  const float* qs   = (const float*)d_in[0];
  const float* ks   = (const float*)d_in[1];
  const float* vs   = (const float*)d_in[2];
  const float* qs_s = (const float*)d_in[3];
  const float* ks_s = (const float*)d_in[4];
  const float* W    = (const float*)d_in[5];
  const float* proj = (const float*)d_in[6];
  const float* a    = (const float*)d_in[7];
  float* out = (float*)d_out;

  char* ws = (char*)d_ws;
  unsigned short* projF = (unsigned short*)(ws + OFF_PROJF);
  unsigned short* vF    = (unsigned short*)(ws + OFF_VF);
  float*          parts = (float*)(ws + OFF_PARTS);
  unsigned short* b1F   = (unsigned short*)(ws + OFF_B1F);

  prep_vF<<<dim3(65, 32), 256, 0, stream>>>(vs, proj, vF, projF);
  f1_k<<<dim3(32, 16), 512, 0, stream>>>(ks, ks_s, W, projF, vF, parts);
  reduce_t<<<dim3(32, 4), 256, 0, stream>>>(parts, b1F);
  f2_k<<<dim3(32, 16), 512, 0, stream>>>(qs, qs_s, W, a, projF, b1F, out);
}

// Round 9
// 92.608 us; speedup vs baseline: 1.7841x; 1.0071x over previous
//
#include <hip/hip_runtime.h>
#include <hip/hip_bf16.h>
#include <math.h>

// Problem dims (fixed by setup_inputs)
#define BB 4
#define LLEN 4096
#define HH 8
#define MM 256
#define KX 96          // padded x-dim: 64 qk + 8 fourier + [72]=hq(-1 col) + zeros
#define EE 80          // padded c-dim: 64 v + 1 ones + 15 zero
#define NTOK 16384     // BB*LLEN
#define NORM 0.35355339059327373f   // 64^-0.25 (folded into projF cols 0..63)
#define NORM2 0.125f                // NORM^2
#define LN16 2.7725887222397811f    // ln(sqrt(256)) folded into h => exp includes 1/sqrt(m)
#define EPSV 1e-6f
#define TWO_PI_F 6.283185307179586f

typedef __attribute__((ext_vector_type(8))) short s16x8;   // 8 bf16 (4 VGPRs)
typedef __attribute__((ext_vector_type(4))) short s16x4;   // 4 bf16
typedef __attribute__((ext_vector_type(4))) float f32x4;   // MFMA acc
typedef __attribute__((ext_vector_type(4))) unsigned int u32x4;

#define MFMA16(A,B,C) __builtin_amdgcn_mfma_f32_16x16x32_bf16(A,B,C,0,0,0)

static __device__ __forceinline__ unsigned short f2bf(float f) {
  union { float f; unsigned int u; } v; v.f = f;
  unsigned int r = v.u + 0x7FFFu + ((v.u >> 16) & 1u);   // round-to-nearest-even
  return (unsigned short)(r >> 16);
}

// ---- workspace byte offsets ----
#define OFF_PROJF 0u
#define OFF_VF    524288u                 // 20971520 B
#define OFF_PARTS (OFF_VF + 20971520u)    // 41943040 B
#define OFF_B1F   (OFF_PARTS + 41943040u) // 1310720 B

// ---------------------------------------------------------------------------
// prep_vF (+ projF build in the extra kc==64 block).
// vF fragment-major: [bh][kslot(128)][ne(5)][lane][8]:
//   value = c[e=(l&15)+16ne][k = 32*kslot + 16*(j>>2) + 4*(l>>4) + (j&3)]
// projF fragment-major: chunk c = mt*3+xs, lane l, j:
//   projLogical[(l&15)+16mt][32xs+8(l>>4)+j]; cols: 0..63 proj*NORM,
//   64..71 proj, 72 = -1 (hq fold), 73..95 = 0.
// ---------------------------------------------------------------------------
__global__ __launch_bounds__(256) void prep_vF(const float* __restrict__ vs,
                                               const float* __restrict__ proj,
                                               unsigned short* __restrict__ vF,
                                               unsigned short* __restrict__ projF) {
  int kc = blockIdx.x;   // 0..63 vF chunks; 64 = projF block
  int bh = blockIdx.y;   // 0..31
  if (kc == 64) {
    if (bh != 0) return;
    int t = threadIdx.x;
    int l = t & 63, grp = t >> 6;
    int l15 = l & 15, l4 = l >> 4;
    for (int c = grp; c < 48; c += 4) {
      int mt = c / 3, xs = c % 3;
      int m = l15 + 16 * mt;
      s16x8 o;
#pragma unroll
      for (int j = 0; j < 8; ++j) {
        int d = 32 * xs + 8 * l4 + j;
        unsigned short u;
        if (d < 64)       u = f2bf(proj[m * 72 + d] * NORM);
        else if (d < 72)  u = f2bf(proj[m * 72 + d]);
        else if (d == 72) u = 0xBF80;  // bf16(-1)
        else              u = 0;
        o[j] = (short)u;
      }
      *reinterpret_cast<s16x8*>(projF + ((size_t)c * 64 + l) * 8) = o;
    }
    return;
  }
  int b = bh >> 3, h = bh & 7;
  int t = threadIdx.x;
  __shared__ unsigned short tile[64][72];
  int k = t >> 2, seg = t & 3;
  const f32x4* src = reinterpret_cast<const f32x4*>(
      vs + (((size_t)(b * LLEN + kc * 64 + k)) * HH + h) * 64 + seg * 16);
#pragma unroll
  for (int j = 0; j < 4; ++j) {
    f32x4 v = src[j];
#pragma unroll
    for (int i = 0; i < 4; ++i) tile[k][seg * 16 + j * 4 + i] = f2bf(v[i]);
  }
  __syncthreads();
  int l = t & 63, ks2 = (t >> 6) & 1, rep = t >> 7;
  int l15 = l & 15, l4 = l >> 4;
  int nelo = rep ? 3 : 0, nehi = rep ? 5 : 3;
  for (int ne = nelo; ne < nehi; ++ne) {
    int e = l15 + 16 * ne;
    s16x8 o;
#pragma unroll
    for (int j = 0; j < 8; ++j) {
      int kl = 32 * ks2 + 16 * (j >> 2) + 4 * l4 + (j & 3);
      unsigned short u;
      if (e < 64)       u = tile[kl][e];
      else if (e == 64) u = 0x3F80;  // bf16(1.0)
      else              u = 0;
      o[j] = (short)u;
    }
    size_t kslot = (size_t)kc * 2 + ks2;
    *reinterpret_cast<s16x8*>(
        vF + (((size_t)bh * 128 + kslot) * 5 + ne) * 64 * 8 + (size_t)l * 8) = o;
  }
}

// ---------------------------------------------------------------------------
// F1: fused {ks f32->bf16 + fourier + hk} staging + phi_k GEMM + exp + buf1
// GEMM. 512 threads (8 waves, 2 mt each). LDS: projF 48K + dbuf {ks tile 8K
// swizzled, vF kslot 5K} + hk 2x32 f32. Direct ks reads — no Xk buffer.
// ---------------------------------------------------------------------------
__global__ __launch_bounds__(512, 2) void f1_k(
    const float* __restrict__ ks, const float* __restrict__ ks_s,
    const float* __restrict__ W,
    const unsigned short* __restrict__ projF,
    const unsigned short* __restrict__ vF,
    float* __restrict__ parts) {
  __shared__ unsigned short pf_lds[24576];       // 48 KB
  __shared__ unsigned char  sbuf[2][13312];      // [0..8191]=ks tile, [8192..]=vF kslot
  __shared__ alignas(16) float hk_sh[2][32];

  int bh = blockIdx.x, split = blockIdx.y;
  int b = bh >> 3, h = bh & 7;
  int tid = threadIdx.x;
  int w = tid >> 6, l = tid & 63;
  int l15 = l & 15, l4 = l >> 4;
  int kbase = split * 256;
  int row = tid >> 4, seg = tid & 15;
  int s4 = (row & 7) << 4;

  const float* ksb = ks + ((size_t)(b * LLEN + kbase) * HH + h) * 64;  // row stride 512 f32
  const float* kss = ks_s + (size_t)b * LLEN + kbase;
  const unsigned short* vfb = vF + ((size_t)bh * 128 + split * 8) * 5 * 64 * 8;

  // per-thread fourier constants (seg<8 threads own fourier element seg)
  float wv = 0.f; bool issin = false;
  if (seg < 8) { int dim = 8 * h + seg; wv = W[dim & 31] * TWO_PI_F; issin = dim < 32; }

  // ---- prologue: zero upper 128B of every row (both bufs) + stage projF ----
  {
    int bi = tid >> 8, rem = tid & 255;
    u32x4 z = {};
    *reinterpret_cast<u32x4*>(&sbuf[bi][(rem >> 3) * 256 + 128 + (rem & 7) * 16]) = z;
    const u32x4* g1 = reinterpret_cast<const u32x4*>(projF);
    u32x4* s1 = reinterpret_cast<u32x4*>(pf_lds);
#pragma unroll
    for (int i = 0; i < 6; ++i) s1[i * 512 + tid] = g1[i * 512 + tid];
  }
  __syncthreads();
  // ---- stage tile 0 + vF slice 0 ----
  {
    f32x4 kv = *reinterpret_cast<const f32x4*>(ksb + (size_t)row * 512 + 4 * seg);
    float part = (kv[0]*kv[0] + kv[1]*kv[1] + kv[2]*kv[2] + kv[3]*kv[3]) * NORM2;
    s16x4 o;
#pragma unroll
    for (int i = 0; i < 4; ++i) o[i] = (short)f2bf(kv[i]);
    *reinterpret_cast<s16x4*>(&sbuf[0][row * 256 + ((8 * seg) ^ s4)]) = o;
    if (seg < 8) {
      float ph = kss[row] * wv;
      float e = issin ? sinf(ph) : cosf(ph);
      part += e * e;
      *reinterpret_cast<unsigned short*>(&sbuf[0][row * 256 + ((128 + 2 * seg) ^ s4)]) = f2bf(e);
    }
#pragma unroll
    for (int m = 1; m < 16; m <<= 1) part += __shfl_xor(part, m, 64);
    if (seg == 0) hk_sh[0][row] = 0.5f * part + LN16;
    if (tid < 320)
      *reinterpret_cast<u32x4*>(&sbuf[0][8192 + tid * 16]) =
          reinterpret_cast<const u32x4*>(vfb)[tid];
  }
  __syncthreads();

  f32x4 acc2[2][5] = {};

  for (int it = 0; it < 8; ++it) {
    int cur = it & 1, nxt = cur ^ 1;
    // issue-early: next tile global loads
    f32x4 kvn; float svn = 0.f; u32x4 nv;
    if (it < 7) {
      kvn = *reinterpret_cast<const f32x4*>(
          ksb + (size_t)(32 * (it + 1) + row) * 512 + 4 * seg);
      if (seg < 8) svn = kss[32 * (it + 1) + row];
      if (tid < 320)
        nv = reinterpret_cast<const u32x4*>(vfb + (size_t)(it + 1) * 2560)[tid];
    }

    // ---- GEMM1: P = Xk . projF^T ----
    s16x8 ak0[3], ak1[3], pf0[3], pf1[3];
#pragma unroll
    for (int xs = 0; xs < 3; ++xs) {
      int co = (64 * xs + 16 * l4) ^ ((l15 & 7) << 4);
      ak0[xs] = *reinterpret_cast<const s16x8*>(&sbuf[cur][l15 * 256 + co]);
      ak1[xs] = *reinterpret_cast<const s16x8*>(&sbuf[cur][(16 + l15) * 256 + co]);
      pf0[xs] = *reinterpret_cast<const s16x8*>(pf_lds + (((2 * w) * 3 + xs) * 64 + l) * 8);
      pf1[xs] = *reinterpret_cast<const s16x8*>(pf_lds + (((2 * w + 1) * 3 + xs) * 64 + l) * 8);
    }
    f32x4 acc1[2][2] = {};
#pragma unroll
    for (int xs = 0; xs < 3; ++xs) {
      acc1[0][0] = MFMA16(ak0[xs], pf0[xs], acc1[0][0]);
      acc1[0][1] = MFMA16(ak0[xs], pf1[xs], acc1[0][1]);
      acc1[1][0] = MFMA16(ak1[xs], pf0[xs], acc1[1][0]);
      acc1[1][1] = MFMA16(ak1[xs], pf1[xs], acc1[1][1]);
    }
    // ---- exp -> bf16 A-frag (k-perm: slot(l4,j) <-> key 16(j>>2)+4l4+(j&3)) ----
    f32x4 hk0 = *reinterpret_cast<const f32x4*>(&hk_sh[cur][4 * l4]);
    f32x4 hk1 = *reinterpret_cast<const f32x4*>(&hk_sh[cur][16 + 4 * l4]);
    s16x8 pa[2];
#pragma unroll
    for (int nt = 0; nt < 2; ++nt)
#pragma unroll
      for (int r = 0; r < 4; ++r) {
        pa[nt][r]     = (short)f2bf(__expf(acc1[0][nt][r] - hk0[r]));
        pa[nt][4 + r] = (short)f2bf(__expf(acc1[1][nt][r] - hk1[r]));
      }
    // ---- GEMM2: acc2 += P^T . c ----
#pragma unroll
    for (int ne = 0; ne < 5; ++ne) {
      s16x8 vb = *reinterpret_cast<const s16x8*>(&sbuf[cur][8192 + (ne * 64 + l) * 16]);
      acc2[0][ne] = MFMA16(pa[0], vb, acc2[0][ne]);
      acc2[1][ne] = MFMA16(pa[1], vb, acc2[1][ne]);
    }
    // ---- write-late: convert + fourier + hk for next tile ----
    if (it < 7) {
      float part = (kvn[0]*kvn[0] + kvn[1]*kvn[1] + kvn[2]*kvn[2] + kvn[3]*kvn[3]) * NORM2;
      s16x4 o;
#pragma unroll
      for (int i = 0; i < 4; ++i) o[i] = (short)f2bf(kvn[i]);
      *reinterpret_cast<s16x4*>(&sbuf[nxt][row * 256 + ((8 * seg) ^ s4)]) = o;
      if (seg < 8) {
        float ph = svn * wv;
        float e = issin ? sinf(ph) : cosf(ph);
        part += e * e;
        *reinterpret_cast<unsigned short*>(&sbuf[nxt][row * 256 + ((128 + 2 * seg) ^ s4)]) = f2bf(e);
      }
#pragma unroll
      for (int m = 1; m < 16; m <<= 1) part += __shfl_xor(part, m, 64);
      if (seg == 0) hk_sh[nxt][row] = 0.5f * part + LN16;
      if (tid < 320) *reinterpret_cast<u32x4*>(&sbuf[nxt][8192 + tid * 16]) = nv;
    }
    __syncthreads();
  }

#pragma unroll
  for (int nt = 0; nt < 2; ++nt)
#pragma unroll
    for (int ne = 0; ne < 5; ++ne)
#pragma unroll
      for (int r = 0; r < 4; ++r) {
        int m = 16 * (2 * w + nt) + 4 * l4 + r;
        parts[(((size_t)split * 32 + bh) * MM + m) * EE + l15 + 16 * ne] = acc2[nt][ne][r];
      }
}

// ---------------------------------------------------------------------------
// reduce 16 splits -> b1F fragment-major [bh][ks(8)][ne(5)][lane][8] bf16
// ---------------------------------------------------------------------------
__global__ __launch_bounds__(256) void reduce_t(const float* __restrict__ parts,
                                                unsigned short* __restrict__ b1F) {
  int bh = blockIdx.x;   // 32
  int mc = blockIdx.y;   // 4 (64 m each)
  __shared__ float s[64 * 80];
  size_t base = ((size_t)bh * MM + mc * 64) * EE;
  for (int o = threadIdx.x; o < 64 * 80; o += 256) {
    float sum = 0.f;
#pragma unroll
    for (int sp = 0; sp < 16; ++sp)
      sum += parts[(size_t)sp * 32 * MM * EE + base + o];
    s[o] = sum;
  }
  __syncthreads();
  int t = threadIdx.x, l = t & 63, kl = (t >> 6) & 1, rep = t >> 7;
  int l15 = l & 15, l4 = l >> 4;
  int nelo = rep ? 3 : 0, nehi = rep ? 5 : 3;
  for (int ne = nelo; ne < nehi; ++ne) {
    s16x8 o;
#pragma unroll
    for (int j = 0; j < 8; ++j) {
      int ml = 32 * kl + 16 * (j >> 2) + 4 * l4 + (j & 3);
      o[j] = (short)f2bf(s[ml * 80 + l15 + 16 * ne]);
    }
    int ks = mc * 2 + kl;
    *reinterpret_cast<s16x8*>(
        b1F + (((size_t)bh * 8 + ks) * 5 + ne) * 64 * 8 + (size_t)l * 8) = o;
  }
}

// ---------------------------------------------------------------------------
// F2: fused {qs f32->frag + fourier + hq} + phi_q GEMM + exp + output GEMM.
// 1024 threads (16 waves x 32 q = 512 queries/block), grid (32 bh, 8 qc).
// projF 48K + b1F 40K staged ONCE into LDS; ONE barrier; then 8 iterations
// of pure {ds_read + MFMA + exp} — no global loads, no barriers.
// ---------------------------------------------------------------------------
__global__ __launch_bounds__(1024, 1) void f2_k(
    const float* __restrict__ qs, const float* __restrict__ qs_s,
    const float* __restrict__ W, const float* __restrict__ a,
    const unsigned short* __restrict__ projF,
    const unsigned short* __restrict__ b1F, float* __restrict__ out) {
  __shared__ unsigned short pf_lds[24576];   // 48 KB
  __shared__ unsigned short b1_lds[20480];   // 40 KB

  int bh = blockIdx.x, qc = blockIdx.y;      // qc: 0..7
  int b = bh >> 3, h = bh & 7;
  int tid = threadIdx.x;
  int w = tid >> 6, l = tid & 63;            // w: 0..15
  int l15 = l & 15, l4 = l >> 4;
  int qb = qc * 512 + w * 32;                // wave's 32 queries
  const unsigned short* b1b = b1F + (size_t)bh * 8 * 5 * 64 * 8;
  float ah = a[h];

  // ---- stage projF (3072 u32x4) + b1F slice (2560 u32x4), once ----
  {
    const u32x4* g1 = reinterpret_cast<const u32x4*>(projF);
    u32x4* s1 = reinterpret_cast<u32x4*>(pf_lds);
#pragma unroll
    for (int i = 0; i < 3; ++i) s1[i * 1024 + tid] = g1[i * 1024 + tid];
    const u32x4* g2 = reinterpret_cast<const u32x4*>(b1b);
    u32x4* s2 = reinterpret_cast<u32x4*>(b1_lds);
    s2[tid] = g2[tid];
    s2[1024 + tid] = g2[1024 + tid];
    if (tid < 512) s2[2048 + tid] = g2[2048 + tid];
  }

  // ---- build xq frags + hq in registers, straight from qs f32 ----
  s16x8 xq[2][3];
#pragma unroll
  for (int qt = 0; qt < 2; ++qt) {
    int qrow = qb + 16 * qt + l15;
    const float* qr = qs + ((size_t)(b * LLEN + qrow) * HH + h) * 64;
    float part = 0.f;
#pragma unroll
    for (int xs = 0; xs < 2; ++xs) {
      f32x4 u0 = *reinterpret_cast<const f32x4*>(qr + 32 * xs + 8 * l4);
      f32x4 u1 = *reinterpret_cast<const f32x4*>(qr + 32 * xs + 8 * l4 + 4);
      s16x8 fr;
#pragma unroll
      for (int i = 0; i < 4; ++i) {
        part += u0[i] * u0[i] + u1[i] * u1[i];
        fr[i] = (short)f2bf(u0[i]);
        fr[4 + i] = (short)f2bf(u1[i]);
      }
      xq[qt][xs] = fr;
    }
    part *= NORM2;
    s16x8 fx = {};
    if (l4 == 0) {
      float sv = qs_s[(size_t)b * LLEN + qrow] * TWO_PI_F;
#pragma unroll
      for (int j = 0; j < 8; ++j) {
        int dim = 8 * h + j;
        float ph = sv * W[dim & 31];
        float e = (dim < 32) ? sinf(ph) : cosf(ph);
        e *= ah;
        part += e * e;
        fx[j] = (short)f2bf(e);
      }
    }
    part += __shfl_xor(part, 16, 64);
    part += __shfl_xor(part, 32, 64);
    if (l4 == 1) fx[0] = (short)f2bf(0.5f * part + LN16);
    xq[qt][2] = fx;
  }
  __syncthreads();

  // ---- 8 iterations, pure LDS + MFMA + exp ----
  f32x4 acc3[2][5] = {};
#pragma unroll
  for (int ks = 0; ks < 8; ++ks) {
    f32x4 a0 = {}, b0 = {}, a1 = {}, b1 = {};
#pragma unroll
    for (int xs = 0; xs < 3; ++xs) {
      s16x8 p0 = *reinterpret_cast<const s16x8*>(pf_lds + (((2 * ks) * 3 + xs) * 64 + l) * 8);
      s16x8 p1 = *reinterpret_cast<const s16x8*>(pf_lds + (((2 * ks + 1) * 3 + xs) * 64 + l) * 8);
      a0 = MFMA16(p0, xq[0][xs], a0);
      b0 = MFMA16(p1, xq[0][xs], b0);
      a1 = MFMA16(p0, xq[1][xs], a1);
      b1 = MFMA16(p1, xq[1][xs], b1);
    }
    s16x8 pa0, pa1;
#pragma unroll
    for (int r = 0; r < 4; ++r) {
      pa0[r]     = (short)f2bf(__expf(a0[r]));
      pa0[4 + r] = (short)f2bf(__expf(b0[r]));
      pa1[r]     = (short)f2bf(__expf(a1[r]));
      pa1[4 + r] = (short)f2bf(__expf(b1[r]));
    }
#pragma unroll
    for (int ne = 0; ne < 5; ++ne) {
      s16x8 vb = *reinterpret_cast<const s16x8*>(b1_lds + ((ks * 5 + ne) * 64 + l) * 8);
      acc3[0][ne] = MFMA16(pa0, vb, acc3[0][ne]);
      acc3[1][ne] = MFMA16(pa1, vb, acc3[1][ne]);
    }
  }
#pragma unroll
  for (int qt = 0; qt < 2; ++qt) {
    float inv[4];
#pragma unroll
    for (int r = 0; r < 4; ++r) {
      float den = __shfl(acc3[qt][4][r], 16 * l4, 64);   // e=64 lives in lanes l15==0
      den = den < EPSV ? EPSV : den;
      inv[r] = 1.0f / den;
    }
#pragma unroll
    for (int ne = 0; ne < 4; ++ne)
#pragma unroll
      for (int r = 0; r < 4; ++r)
        out[((size_t)(b * LLEN + qb + 16 * qt + 4 * l4 + r) * HH + h) * 64 + l15 + 16 * ne] =
            acc3[qt][ne][r] * inv[r];
  }
}

// ---------------------------------------------------------------------------
extern "C" void kernel_launch(void* const* d_in, const int* in_sizes, int n_in,
                              void* d_out, int out_size, void* d_ws, size_t ws_size,
                              hipStream_t stream) {
  const float* qs   = (const float*)d_in[0];
  const float* ks   = (const float*)d_in[1];
  const float* vs   = (const float*)d_in[2];
  const float* qs_s = (const float*)d_in[3];
  const float* ks_s = (const float*)d_in[4];
  const float* W    = (const float*)d_in[5];
  const float* proj = (const float*)d_in[6];
  const float* a    = (const float*)d_in[7];
  float* out = (float*)d_out;

  char* ws = (char*)d_ws;
  unsigned short* projF = (unsigned short*)(ws + OFF_PROJF);
  unsigned short* vF    = (unsigned short*)(ws + OFF_VF);
  float*          parts = (float*)(ws + OFF_PARTS);
  unsigned short* b1F   = (unsigned short*)(ws + OFF_B1F);

  prep_vF<<<dim3(65, 32), 256, 0, stream>>>(vs, proj, vF, projF);
  f1_k<<<dim3(32, 16), 512, 0, stream>>>(ks, ks_s, W, projF, vF, parts);
  reduce_t<<<dim3(32, 4), 256, 0, stream>>>(parts, b1F);
  f2_k<<<dim3(32, 8), 1024, 0, stream>>>(qs, qs_s, W, a, projF, b1F, out);
}

// Round 10
// 79.397 us; speedup vs baseline: 2.0810x; 1.1664x over previous
//
#include <hip/hip_runtime.h>
#include <hip/hip_bf16.h>
#include <math.h>

// Problem dims (fixed by setup_inputs)
#define BB 4
#define LLEN 4096
#define HH 8
#define MM 256
#define KX 96          // padded x-dim: 64 qk + 8 fourier + [72]=hq(-1 col) + zeros
#define EE 80          // padded c-dim: 64 v + 1 ones + 15 zero
#define NTOK 16384     // BB*LLEN
#define NORM 0.35355339059327373f   // 64^-0.25 (folded into projF cols 0..63)
#define NORM2 0.125f                // NORM^2
#define LN16 2.7725887222397811f    // ln(sqrt(256)) folded into h => exp includes 1/sqrt(m)
#define EPSV 1e-6f
#define TWO_PI_F 6.283185307179586f
#define NSPLIT 8

typedef __attribute__((ext_vector_type(8))) short s16x8;   // 8 bf16 (4 VGPRs)
typedef __attribute__((ext_vector_type(4))) short s16x4;   // 4 bf16
typedef __attribute__((ext_vector_type(4))) float f32x4;   // MFMA acc
typedef __attribute__((ext_vector_type(4))) unsigned int u32x4;

#define MFMA16(A,B,C) __builtin_amdgcn_mfma_f32_16x16x32_bf16(A,B,C,0,0,0)

static __device__ __forceinline__ unsigned short f2bf(float f) {
  union { float f; unsigned int u; } v; v.f = f;
  unsigned int r = v.u + 0x7FFFu + ((v.u >> 16) & 1u);   // round-to-nearest-even
  return (unsigned short)(r >> 16);
}
// pair convert+pack via HW v_cvt_pk_bf16_f32 (RNE, same bits as f2bf)
static __device__ __forceinline__ unsigned int pk2(float lo, float hi) {
  __hip_bfloat162 h = __float22bfloat162_rn(make_float2(lo, hi));
  union { __hip_bfloat162 h; unsigned int u; } c; c.h = h;
  return c.u;
}

// ---- workspace byte offsets ----
#define OFF_PROJF 0u
#define OFF_VF    524288u                 // 20971520 B
#define OFF_PARTS (OFF_VF + 20971520u)    // 20971520 B (NSPLIT=8)
#define OFF_B1F   (OFF_PARTS + 41943040u) // 1310720 B

// ---------------------------------------------------------------------------
// prep_vF (+ projF build in the extra kc==64 block).  (unchanged)
// ---------------------------------------------------------------------------
__global__ __launch_bounds__(256) void prep_vF(const float* __restrict__ vs,
                                               const float* __restrict__ proj,
                                               unsigned short* __restrict__ vF,
                                               unsigned short* __restrict__ projF) {
  int kc = blockIdx.x;   // 0..63 vF chunks; 64 = projF block
  int bh = blockIdx.y;   // 0..31
  if (kc == 64) {
    if (bh != 0) return;
    int t = threadIdx.x;
    int l = t & 63, grp = t >> 6;
    int l15 = l & 15, l4 = l >> 4;
    for (int c = grp; c < 48; c += 4) {
      int mt = c / 3, xs = c % 3;
      int m = l15 + 16 * mt;
      s16x8 o;
#pragma unroll
      for (int j = 0; j < 8; ++j) {
        int d = 32 * xs + 8 * l4 + j;
        unsigned short u;
        if (d < 64)       u = f2bf(proj[m * 72 + d] * NORM);
        else if (d < 72)  u = f2bf(proj[m * 72 + d]);
        else if (d == 72) u = 0xBF80;  // bf16(-1)
        else              u = 0;
        o[j] = (short)u;
      }
      *reinterpret_cast<s16x8*>(projF + ((size_t)c * 64 + l) * 8) = o;
    }
    return;
  }
  int b = bh >> 3, h = bh & 7;
  int t = threadIdx.x;
  __shared__ unsigned short tile[64][72];
  int k = t >> 2, seg = t & 3;
  const f32x4* src = reinterpret_cast<const f32x4*>(
      vs + (((size_t)(b * LLEN + kc * 64 + k)) * HH + h) * 64 + seg * 16);
#pragma unroll
  for (int j = 0; j < 4; ++j) {
    f32x4 v = src[j];
#pragma unroll
    for (int i = 0; i < 4; ++i) tile[k][seg * 16 + j * 4 + i] = f2bf(v[i]);
  }
  __syncthreads();
  int l = t & 63, ks2 = (t >> 6) & 1, rep = t >> 7;
  int l15 = l & 15, l4 = l >> 4;
  int nelo = rep ? 3 : 0, nehi = rep ? 5 : 3;
  for (int ne = nelo; ne < nehi; ++ne) {
    int e = l15 + 16 * ne;
    s16x8 o;
#pragma unroll
    for (int j = 0; j < 8; ++j) {
      int kl = 32 * ks2 + 16 * (j >> 2) + 4 * l4 + (j & 3);
      unsigned short u;
      if (e < 64)       u = tile[kl][e];
      else if (e == 64) u = 0x3F80;  // bf16(1.0)
      else              u = 0;
      o[j] = (short)u;
    }
    size_t kslot = (size_t)kc * 2 + ks2;
    *reinterpret_cast<s16x8*>(
        vF + (((size_t)bh * 128 + kslot) * 5 + ne) * 64 * 8 + (size_t)l * 8) = o;
  }
}

// ---------------------------------------------------------------------------
// F1: fused {ks f32->bf16 + fourier + hk} staging + phi_k GEMM + exp + buf1
// GEMM. NOW: 1024 threads (16 waves, 1 mt each), grid (32 bh, 8 splits) =
// 256 blocks (1/CU, 16 waves/CU — same occupancy as R9's 2x8w). 512 keys per
// block over 16 iterations; parts traffic halved vs NSPLIT=16.
// ---------------------------------------------------------------------------
__global__ __launch_bounds__(1024, 1) void f1_k(
    const float* __restrict__ ks, const float* __restrict__ ks_s,
    const float* __restrict__ W,
    const unsigned short* __restrict__ projF,
    const unsigned short* __restrict__ vF,
    float* __restrict__ parts) {
  __shared__ unsigned short pf_lds[24576];       // 48 KB
  __shared__ unsigned char  sbuf[2][13312];      // [0..8191]=ks tile, [8192..]=vF kslot
  __shared__ alignas(16) float hk_sh[2][32];

  int bh = blockIdx.x, split = blockIdx.y;       // split: 0..7
  int b = bh >> 3, h = bh & 7;
  int tid = threadIdx.x;
  int w = tid >> 6, l = tid & 63;                // w: 0..15, one m-tile each
  int l15 = l & 15, l4 = l >> 4;
  int kbase = split * 512;
  int row = tid >> 4, seg = tid & 15;            // valid rows: tid<512
  int s4 = (row & 7) << 4;

  const float* ksb = ks + ((size_t)(b * LLEN + kbase) * HH + h) * 64;  // row stride 512 f32
  const float* kss = ks_s + (size_t)b * LLEN + kbase;
  const unsigned short* vfb = vF + ((size_t)bh * 128 + split * 16) * 5 * 64 * 8;

  float wv = 0.f; bool issin = false;
  if (seg < 8) { int dim = 8 * h + seg; wv = W[dim & 31] * TWO_PI_F; issin = dim < 32; }

  // ---- prologue: zero upper 128B of every row (both bufs) + stage projF ----
  {
    if (tid < 512) {
      int bi = tid >> 8, rem = tid & 255;
      u32x4 z = {};
      *reinterpret_cast<u32x4*>(&sbuf[bi][(rem >> 3) * 256 + 128 + (rem & 7) * 16]) = z;
    }
    const u32x4* g1 = reinterpret_cast<const u32x4*>(projF);
    u32x4* s1 = reinterpret_cast<u32x4*>(pf_lds);
#pragma unroll
    for (int i = 0; i < 3; ++i) s1[i * 1024 + tid] = g1[i * 1024 + tid];
  }
  __syncthreads();
  // ---- stage tile 0 + vF slice 0 ----
  if (tid < 512) {
    f32x4 kv = *reinterpret_cast<const f32x4*>(ksb + (size_t)row * 512 + 4 * seg);
    float part = (kv[0]*kv[0] + kv[1]*kv[1] + kv[2]*kv[2] + kv[3]*kv[3]) * NORM2;
    s16x4 o;
#pragma unroll
    for (int i = 0; i < 4; ++i) o[i] = (short)f2bf(kv[i]);
    *reinterpret_cast<s16x4*>(&sbuf[0][row * 256 + ((8 * seg) ^ s4)]) = o;
    if (seg < 8) {
      float ph = kss[row] * wv;
      float e = issin ? sinf(ph) : cosf(ph);
      part += e * e;
      *reinterpret_cast<unsigned short*>(&sbuf[0][row * 256 + ((128 + 2 * seg) ^ s4)]) = f2bf(e);
    }
#pragma unroll
    for (int m = 1; m < 16; m <<= 1) part += __shfl_xor(part, m, 64);
    if (seg == 0) hk_sh[0][row] = 0.5f * part + LN16;
  }
  if (tid < 320)
    *reinterpret_cast<u32x4*>(&sbuf[0][8192 + tid * 16]) =
        reinterpret_cast<const u32x4*>(vfb)[tid];
  __syncthreads();

  f32x4 acc2[5] = {};

  for (int it = 0; it < 16; ++it) {
    int cur = it & 1, nxt = cur ^ 1;
    // issue-early: next tile global loads
    f32x4 kvn; float svn = 0.f; u32x4 nv;
    if (it < 15) {
      if (tid < 512) {
        kvn = *reinterpret_cast<const f32x4*>(
            ksb + (size_t)(32 * (it + 1) + row) * 512 + 4 * seg);
        if (seg < 8) svn = kss[32 * (it + 1) + row];
      }
      if (tid < 320)
        nv = reinterpret_cast<const u32x4*>(vfb + (size_t)(it + 1) * 2560)[tid];
    }

    // ---- GEMM1: P = Xk . projF^T (wave's single m-tile) ----
    f32x4 acc1_0 = {}, acc1_1 = {};
#pragma unroll
    for (int xs = 0; xs < 3; ++xs) {
      int co = (64 * xs + 16 * l4) ^ ((l15 & 7) << 4);
      s16x8 ak0 = *reinterpret_cast<const s16x8*>(&sbuf[cur][l15 * 256 + co]);
      s16x8 ak1 = *reinterpret_cast<const s16x8*>(&sbuf[cur][(16 + l15) * 256 + co]);
      s16x8 pf = *reinterpret_cast<const s16x8*>(pf_lds + ((w * 3 + xs) * 64 + l) * 8);
      acc1_0 = MFMA16(ak0, pf, acc1_0);
      acc1_1 = MFMA16(ak1, pf, acc1_1);
    }
    // ---- exp -> bf16 A-frag via cvt_pk pairs ----
    f32x4 hk0 = *reinterpret_cast<const f32x4*>(&hk_sh[cur][4 * l4]);
    f32x4 hk1 = *reinterpret_cast<const f32x4*>(&hk_sh[cur][16 + 4 * l4]);
    union { unsigned int u[4]; s16x8 s; } P;
    P.u[0] = pk2(__expf(acc1_0[0] - hk0[0]), __expf(acc1_0[1] - hk0[1]));
    P.u[1] = pk2(__expf(acc1_0[2] - hk0[2]), __expf(acc1_0[3] - hk0[3]));
    P.u[2] = pk2(__expf(acc1_1[0] - hk1[0]), __expf(acc1_1[1] - hk1[1]));
    P.u[3] = pk2(__expf(acc1_1[2] - hk1[2]), __expf(acc1_1[3] - hk1[3]));
    // ---- GEMM2: acc2 += P^T . c ----
#pragma unroll
    for (int ne = 0; ne < 5; ++ne) {
      s16x8 vb = *reinterpret_cast<const s16x8*>(&sbuf[cur][8192 + (ne * 64 + l) * 16]);
      acc2[ne] = MFMA16(P.s, vb, acc2[ne]);
    }
    // ---- write-late: convert + fourier + hk for next tile ----
    if (it < 15) {
      if (tid < 512) {
        float part = (kvn[0]*kvn[0] + kvn[1]*kvn[1] + kvn[2]*kvn[2] + kvn[3]*kvn[3]) * NORM2;
        s16x4 o;
#pragma unroll
        for (int i = 0; i < 4; ++i) o[i] = (short)f2bf(kvn[i]);
        *reinterpret_cast<s16x4*>(&sbuf[nxt][row * 256 + ((8 * seg) ^ s4)]) = o;
        if (seg < 8) {
          float ph = svn * wv;
          float e = issin ? sinf(ph) : cosf(ph);
          part += e * e;
          *reinterpret_cast<unsigned short*>(&sbuf[nxt][row * 256 + ((128 + 2 * seg) ^ s4)]) = f2bf(e);
        }
#pragma unroll
        for (int m = 1; m < 16; m <<= 1) part += __shfl_xor(part, m, 64);
        if (seg == 0) hk_sh[nxt][row] = 0.5f * part + LN16;
      }
      if (tid < 320) *reinterpret_cast<u32x4*>(&sbuf[nxt][8192 + tid * 16]) = nv;
    }
    __syncthreads();
  }

#pragma unroll
  for (int ne = 0; ne < 5; ++ne)
#pragma unroll
    for (int r = 0; r < 4; ++r) {
      int m = 16 * w + 4 * l4 + r;
      parts[(((size_t)split * 32 + bh) * MM + m) * EE + l15 + 16 * ne] = acc2[ne][r];
    }
}

// ---------------------------------------------------------------------------
// reduce 8 splits -> b1F fragment-major [bh][ks(8)][ne(5)][lane][8] bf16
// ---------------------------------------------------------------------------
__global__ __launch_bounds__(256) void reduce_t(const float* __restrict__ parts,
                                                unsigned short* __restrict__ b1F) {
  int bh = blockIdx.x;   // 32
  int mc = blockIdx.y;   // 4 (64 m each)
  __shared__ float s[64 * 80];
  size_t base = ((size_t)bh * MM + mc * 64) * EE;
  for (int o = threadIdx.x; o < 64 * 80; o += 256) {
    float sum = 0.f;
#pragma unroll
    for (int sp = 0; sp < NSPLIT; ++sp)
      sum += parts[(size_t)sp * 32 * MM * EE + base + o];
    s[o] = sum;
  }
  __syncthreads();
  int t = threadIdx.x, l = t & 63, kl = (t >> 6) & 1, rep = t >> 7;
  int l15 = l & 15, l4 = l >> 4;
  int nelo = rep ? 3 : 0, nehi = rep ? 5 : 3;
  for (int ne = nelo; ne < nehi; ++ne) {
    s16x8 o;
#pragma unroll
    for (int j = 0; j < 8; ++j) {
      int ml = 32 * kl + 16 * (j >> 2) + 4 * l4 + (j & 3);
      o[j] = (short)f2bf(s[ml * 80 + l15 + 16 * ne]);
    }
    int ks = mc * 2 + kl;
    *reinterpret_cast<s16x8*>(
        b1F + (((size_t)bh * 8 + ks) * 5 + ne) * 64 * 8 + (size_t)l * 8) = o;
  }
}

// ---------------------------------------------------------------------------
// F2: fused {qs f32->frag + fourier + hq} + phi_q GEMM + exp + output GEMM.
// 1024 threads (16 waves x 32 q), grid (32 bh, 8 qc). Monolithic stage, one
// barrier, barrier-free inner loop. NEW: cvt_pk epilogue + setprio on MFMA
// clusters (independent waves -> attn-like regime, m191).
// ---------------------------------------------------------------------------
__global__ __launch_bounds__(1024, 1) void f2_k(
    const float* __restrict__ qs, const float* __restrict__ qs_s,
    const float* __restrict__ W, const float* __restrict__ a,
    const unsigned short* __restrict__ projF,
    const unsigned short* __restrict__ b1F, float* __restrict__ out) {
  __shared__ unsigned short pf_lds[24576];   // 48 KB
  __shared__ unsigned short b1_lds[20480];   // 40 KB

  int bh = blockIdx.x, qc = blockIdx.y;      // qc: 0..7
  int b = bh >> 3, h = bh & 7;
  int tid = threadIdx.x;
  int w = tid >> 6, l = tid & 63;            // w: 0..15
  int l15 = l & 15, l4 = l >> 4;
  int qb = qc * 512 + w * 32;                // wave's 32 queries
  const unsigned short* b1b = b1F + (size_t)bh * 8 * 5 * 64 * 8;
  float ah = a[h];

  // ---- stage projF (3072 u32x4) + b1F slice (2560 u32x4), once ----
  {
    const u32x4* g1 = reinterpret_cast<const u32x4*>(projF);
    u32x4* s1 = reinterpret_cast<u32x4*>(pf_lds);
#pragma unroll
    for (int i = 0; i < 3; ++i) s1[i * 1024 + tid] = g1[i * 1024 + tid];
    const u32x4* g2 = reinterpret_cast<const u32x4*>(b1b);
    u32x4* s2 = reinterpret_cast<u32x4*>(b1_lds);
    s2[tid] = g2[tid];
    s2[1024 + tid] = g2[1024 + tid];
    if (tid < 512) s2[2048 + tid] = g2[2048 + tid];
  }

  // ---- build xq frags + hq in registers, straight from qs f32 ----
  s16x8 xq[2][3];
#pragma unroll
  for (int qt = 0; qt < 2; ++qt) {
    int qrow = qb + 16 * qt + l15;
    const float* qr = qs + ((size_t)(b * LLEN + qrow) * HH + h) * 64;
    float part = 0.f;
#pragma unroll
    for (int xs = 0; xs < 2; ++xs) {
      f32x4 u0 = *reinterpret_cast<const f32x4*>(qr + 32 * xs + 8 * l4);
      f32x4 u1 = *reinterpret_cast<const f32x4*>(qr + 32 * xs + 8 * l4 + 4);
      s16x8 fr;
#pragma unroll
      for (int i = 0; i < 4; ++i) {
        part += u0[i] * u0[i] + u1[i] * u1[i];
        fr[i] = (short)f2bf(u0[i]);
        fr[4 + i] = (short)f2bf(u1[i]);
      }
      xq[qt][xs] = fr;
    }
    part *= NORM2;
    s16x8 fx = {};
    if (l4 == 0) {
      float sv = qs_s[(size_t)b * LLEN + qrow] * TWO_PI_F;
#pragma unroll
      for (int j = 0; j < 8; ++j) {
        int dim = 8 * h + j;
        float ph = sv * W[dim & 31];
        float e = (dim < 32) ? sinf(ph) : cosf(ph);
        e *= ah;
        part += e * e;
        fx[j] = (short)f2bf(e);
      }
    }
    part += __shfl_xor(part, 16, 64);
    part += __shfl_xor(part, 32, 64);
    if (l4 == 1) fx[0] = (short)f2bf(0.5f * part + LN16);
    xq[qt][2] = fx;
  }
  __syncthreads();

  // ---- 8 iterations, pure LDS + MFMA + exp ----
  f32x4 acc3[2][5] = {};
#pragma unroll
  for (int ks = 0; ks < 8; ++ks) {
    f32x4 a0 = {}, b0 = {}, a1 = {}, b1 = {};
    __builtin_amdgcn_s_setprio(1);
#pragma unroll
    for (int xs = 0; xs < 3; ++xs) {
      s16x8 p0 = *reinterpret_cast<const s16x8*>(pf_lds + (((2 * ks) * 3 + xs) * 64 + l) * 8);
      s16x8 p1 = *reinterpret_cast<const s16x8*>(pf_lds + (((2 * ks + 1) * 3 + xs) * 64 + l) * 8);
      a0 = MFMA16(p0, xq[0][xs], a0);
      b0 = MFMA16(p1, xq[0][xs], b0);
      a1 = MFMA16(p0, xq[1][xs], a1);
      b1 = MFMA16(p1, xq[1][xs], b1);
    }
    __builtin_amdgcn_s_setprio(0);
    union { unsigned int u[4]; s16x8 s; } Pa, Pb;
    Pa.u[0] = pk2(__expf(a0[0]), __expf(a0[1]));
    Pa.u[1] = pk2(__expf(a0[2]), __expf(a0[3]));
    Pa.u[2] = pk2(__expf(b0[0]), __expf(b0[1]));
    Pa.u[3] = pk2(__expf(b0[2]), __expf(b0[3]));
    Pb.u[0] = pk2(__expf(a1[0]), __expf(a1[1]));
    Pb.u[1] = pk2(__expf(a1[2]), __expf(a1[3]));
    Pb.u[2] = pk2(__expf(b1[0]), __expf(b1[1]));
    Pb.u[3] = pk2(__expf(b1[2]), __expf(b1[3]));
    __builtin_amdgcn_s_setprio(1);
#pragma unroll
    for (int ne = 0; ne < 5; ++ne) {
      s16x8 vb = *reinterpret_cast<const s16x8*>(b1_lds + ((ks * 5 + ne) * 64 + l) * 8);
      acc3[0][ne] = MFMA16(Pa.s, vb, acc3[0][ne]);
      acc3[1][ne] = MFMA16(Pb.s, vb, acc3[1][ne]);
    }
    __builtin_amdgcn_s_setprio(0);
  }
#pragma unroll
  for (int qt = 0; qt < 2; ++qt) {
    float inv[4];
#pragma unroll
    for (int r = 0; r < 4; ++r) {
      float den = __shfl(acc3[qt][4][r], 16 * l4, 64);   // e=64 lives in lanes l15==0
      den = den < EPSV ? EPSV : den;
      inv[r] = 1.0f / den;
    }
#pragma unroll
    for (int ne = 0; ne < 4; ++ne)
#pragma unroll
      for (int r = 0; r < 4; ++r)
        out[((size_t)(b * LLEN + qb + 16 * qt + 4 * l4 + r) * HH + h) * 64 + l15 + 16 * ne] =
            acc3[qt][ne][r] * inv[r];
  }
}

// ---------------------------------------------------------------------------
extern "C" void kernel_launch(void* const* d_in, const int* in_sizes, int n_in,
                              void* d_out, int out_size, void* d_ws, size_t ws_size,
                              hipStream_t stream) {
  const float* qs   = (const float*)d_in[0];
  const float* ks   = (const float*)d_in[1];
  const float* vs   = (const float*)d_in[2];
  const float* qs_s = (const float*)d_in[3];
  const float* ks_s = (const float*)d_in[4];
  const float* W    = (const float*)d_in[5];
  const float* proj = (const float*)d_in[6];
  const float* a    = (const float*)d_in[7];
  float* out = (float*)d_out;

  char* ws = (char*)d_ws;
  unsigned short* projF = (unsigned short*)(ws + OFF_PROJF);
  unsigned short* vF    = (unsigned short*)(ws + OFF_VF);
  float*          parts = (float*)(ws + OFF_PARTS);
  unsigned short* b1F   = (unsigned short*)(ws + OFF_B1F);

  prep_vF<<<dim3(65, 32), 256, 0, stream>>>(vs, proj, vF, projF);
  f1_k<<<dim3(32, NSPLIT), 1024, 0, stream>>>(ks, ks_s, W, projF, vF, parts);
  reduce_t<<<dim3(32, 4), 256, 0, stream>>>(parts, b1F);
  f2_k<<<dim3(32, 8), 1024, 0, stream>>>(qs, qs_s, W, a, projF, b1F, out);
}

// Round 12
// 73.895 us; speedup vs baseline: 2.2360x; 1.0745x over previous
//
#include <hip/hip_runtime.h>
#include <hip/hip_bf16.h>
#include <math.h>

// Problem dims (fixed by setup_inputs)
#define BB 4
#define LLEN 4096
#define HH 8
#define MM 256
#define KX 96
#define EE 80          // padded c-dim: 64 v + 1 ones + 15 zero
#define NTOK 16384
#define NORM 0.35355339059327373f   // 64^-0.25 (folded into projF cols 0..63)
#define NORM2 0.125f                // NORM^2
#define LN16 2.7725887222397811f    // ln(sqrt(256)) folded into h
#define EPSV 1e-6f
#define TWO_PI_F 6.283185307179586f
#define NSPLIT 8

typedef __attribute__((ext_vector_type(8))) short s16x8;   // 8 bf16 (4 VGPRs)
typedef __attribute__((ext_vector_type(4))) short s16x4;   // 4 bf16 (2 VGPRs)
typedef __attribute__((ext_vector_type(4))) float f32x4;
typedef __attribute__((ext_vector_type(4))) unsigned int u32x4;

#define MFMA16(A,B,C) __builtin_amdgcn_mfma_f32_16x16x32_bf16(A,B,C,0,0,0)

static __device__ __forceinline__ unsigned short f2bf(float f) {
  union { float f; unsigned int u; } v; v.f = f;
  unsigned int r = v.u + 0x7FFFu + ((v.u >> 16) & 1u);   // RNE
  return (unsigned short)(r >> 16);
}
static __device__ __forceinline__ unsigned int pk2(float lo, float hi) {
  __hip_bfloat162 h = __float22bfloat162_rn(make_float2(lo, hi));
  union { __hip_bfloat162 h; unsigned int u; } c; c.h = h;
  return c.u;
}
static __device__ __forceinline__ s16x8 cat4(s16x4 a, s16x4 b) {
  s16x8 r;
  r[0]=a[0]; r[1]=a[1]; r[2]=a[2]; r[3]=a[3];
  r[4]=b[0]; r[5]=b[1]; r[6]=b[2]; r[7]=b[3];
  return r;
}

// ---- workspace byte offsets ----
#define OFF_PROJF 0u
#define OFF_PARTS 524288u
#define OFF_B1F   (OFF_PARTS + 20971520u)   // NSPLIT=8 parts

// ---------------------------------------------------------------------------
// projF fragment-major: chunk c = mt*3+xs, lane l, j:
//   projLogical[(l&15)+16mt][32xs+8(l>>4)+j]; cols: 0..63 proj*NORM,
//   64..71 proj, 72 = -1 (hq fold), 73..95 = 0.
// ---------------------------------------------------------------------------
__global__ __launch_bounds__(256) void prep_projF(const float* __restrict__ proj,
                                                  unsigned short* __restrict__ projF) {
  int t = threadIdx.x;
  int l = t & 63, grp = t >> 6;
  int l15 = l & 15, l4 = l >> 4;
  for (int c = grp; c < 48; c += 4) {
    int mt = c / 3, xs = c % 3;
    int m = l15 + 16 * mt;
    s16x8 o;
#pragma unroll
    for (int j = 0; j < 8; ++j) {
      int d = 32 * xs + 8 * l4 + j;
      unsigned short u;
      if (d < 64)       u = f2bf(proj[m * 72 + d] * NORM);
      else if (d < 72)  u = f2bf(proj[m * 72 + d]);
      else if (d == 72) u = 0xBF80;  // bf16(-1)
      else              u = 0;
      o[j] = (short)u;
    }
    *reinterpret_cast<s16x8*>(projF + ((size_t)c * 64 + l) * 8) = o;
  }
}

// ---------------------------------------------------------------------------
// F1: fused {ks->bf16 + fourier + hk} + phi_k GEMM + exp + buf1 GEMM with
// V delivered via ds_read_b64_tr_b16 from a row-major [ne(4)][k(32)][16e]
// LDS tile. tr_b16 slot model: byte(j) = (A&~127) + 2*((A>>3)&15) + 32*j,
// so lane addr A = base + 128*l4 + 8*l15 selects column l15 of the
// [4k][16e] sub-tile; offset:{0,512}+ne*1024 walks k+16 and ne.
// 1024 threads (16 waves, 1 m-tile each), grid (32 bh, 8 splits).
// ---------------------------------------------------------------------------
__global__ __launch_bounds__(1024, 1) void f1_k(
    const float* __restrict__ ks, const float* __restrict__ ks_s,
    const float* __restrict__ vs, const float* __restrict__ W,
    const unsigned short* __restrict__ projF,
    float* __restrict__ parts) {
  __shared__ unsigned short pf_lds[24576];             // 48 KB
  __shared__ alignas(16) unsigned char sbuf[2][12288]; // [0..8191]=ks tile, [8192..]=v tile
  __shared__ alignas(16) float hk_sh[2][32];

  int bh = blockIdx.x, split = blockIdx.y;
  int b = bh >> 3, h = bh & 7;
  int tid = threadIdx.x;
  int w = tid >> 6, l = tid & 63;
  int l15 = l & 15, l4 = l >> 4;
  int kbase = split * 512;
  int row = tid >> 4, seg = tid & 15;   // staging roles, tid<512
  int s4 = (row & 7) << 4;

  const float* ksb = ks + ((size_t)(b * LLEN + kbase) * HH + h) * 64;  // stride 512 f32/key
  const float* vsb = vs + ((size_t)(b * LLEN + kbase) * HH + h) * 64;
  const float* kss = ks_s + (size_t)b * LLEN + kbase;

  float wv = 0.f; bool issin = false;
  if (seg < 8) { int dim = 8 * h + seg; wv = W[dim & 31] * TWO_PI_F; issin = dim < 32; }

  // v-tile write slot: [ne=seg>>2][k=row][4(seg&3)..+3]
  int vwo = 8192 + (seg >> 2) * 1024 + row * 32 + (seg & 3) * 8;

  // ---- prologue: zero upper 128B of ks rows (both bufs) + stage projF ----
  if (tid < 512) {
    int bi = tid >> 8, rem = tid & 255;
    u32x4 z = {};
    *reinterpret_cast<u32x4*>(&sbuf[bi][(rem >> 3) * 256 + 128 + (rem & 7) * 16]) = z;
  }
  {
    const u32x4* g1 = reinterpret_cast<const u32x4*>(projF);
    u32x4* s1 = reinterpret_cast<u32x4*>(pf_lds);
#pragma unroll
    for (int i = 0; i < 3; ++i) s1[i * 1024 + tid] = g1[i * 1024 + tid];
  }
  __syncthreads();
  // ---- stage tile 0: ks (+fourier+hk) and v ----
  if (tid < 512) {
    f32x4 kv = *reinterpret_cast<const f32x4*>(ksb + (size_t)row * 512 + 4 * seg);
    float part = (kv[0]*kv[0] + kv[1]*kv[1] + kv[2]*kv[2] + kv[3]*kv[3]) * NORM2;
    s16x4 o;
#pragma unroll
    for (int i = 0; i < 4; ++i) o[i] = (short)f2bf(kv[i]);
    *reinterpret_cast<s16x4*>(&sbuf[0][row * 256 + ((8 * seg) ^ s4)]) = o;
    if (seg < 8) {
      float ph = kss[row] * wv;
      float e = issin ? sinf(ph) : cosf(ph);
      part += e * e;
      *reinterpret_cast<unsigned short*>(&sbuf[0][row * 256 + ((128 + 2 * seg) ^ s4)]) = f2bf(e);
    }
#pragma unroll
    for (int m = 1; m < 16; m <<= 1) part += __shfl_xor(part, m, 64);
    if (seg == 0) hk_sh[0][row] = 0.5f * part + LN16;
    f32x4 vv = *reinterpret_cast<const f32x4*>(vsb + (size_t)row * 512 + 4 * seg);
    uint2 vp = make_uint2(pk2(vv[0], vv[1]), pk2(vv[2], vv[3]));
    *reinterpret_cast<uint2*>(&sbuf[0][vwo]) = vp;
  }
  __syncthreads();

  // constant ne=4 B-frag: c[k][e=64+l15] = (l15==0) ? 1 : 0
  s16x8 vb4 = {};
  if (l15 == 0) {
#pragma unroll
    for (int j = 0; j < 8; ++j) vb4[j] = (short)0x3F80;
  }

  f32x4 acc2[5] = {};

  for (int it = 0; it < 16; ++it) {
    int cur = it & 1, nxt = cur ^ 1;
    // issue-early: next-tile global loads
    f32x4 kvn, vvn; float svn = 0.f;
    if (it < 15 && tid < 512) {
      kvn = *reinterpret_cast<const f32x4*>(ksb + (size_t)(32 * (it + 1) + row) * 512 + 4 * seg);
      vvn = *reinterpret_cast<const f32x4*>(vsb + (size_t)(32 * (it + 1) + row) * 512 + 4 * seg);
      if (seg < 8) svn = kss[32 * (it + 1) + row];
    }

    // ---- GEMM1: P = Xk . projF^T (wave's single m-tile) ----
    f32x4 acc1_0 = {}, acc1_1 = {};
#pragma unroll
    for (int xs = 0; xs < 3; ++xs) {
      int co = (64 * xs + 16 * l4) ^ ((l15 & 7) << 4);
      s16x8 ak0 = *reinterpret_cast<const s16x8*>(&sbuf[cur][l15 * 256 + co]);
      s16x8 ak1 = *reinterpret_cast<const s16x8*>(&sbuf[cur][(16 + l15) * 256 + co]);
      s16x8 pf = *reinterpret_cast<const s16x8*>(pf_lds + ((w * 3 + xs) * 64 + l) * 8);
      acc1_0 = MFMA16(ak0, pf, acc1_0);
      acc1_1 = MFMA16(ak1, pf, acc1_1);
    }
    // ---- exp -> bf16 A-frag ----
    f32x4 hk0 = *reinterpret_cast<const f32x4*>(&hk_sh[cur][4 * l4]);
    f32x4 hk1 = *reinterpret_cast<const f32x4*>(&hk_sh[cur][16 + 4 * l4]);
    union { unsigned int u[4]; s16x8 s; } P;
    P.u[0] = pk2(__expf(acc1_0[0] - hk0[0]), __expf(acc1_0[1] - hk0[1]));
    P.u[1] = pk2(__expf(acc1_0[2] - hk0[2]), __expf(acc1_0[3] - hk0[3]));
    P.u[2] = pk2(__expf(acc1_1[0] - hk1[0]), __expf(acc1_1[1] - hk1[1]));
    P.u[3] = pk2(__expf(acc1_1[2] - hk1[2]), __expf(acc1_1[3] - hk1[3]));

    // ---- GEMM2 B-frags via HW transpose-read from v tile ----
    // slot model: column select = (A>>3)&15  =>  A = base + 128*l4 + 8*l15
    unsigned int va = (unsigned int)(size_t)(&sbuf[cur][8192]) + 8 * l15 + 128 * l4;
    s16x4 t0, t1, t2, t3, t4, t5, t6, t7;
    asm volatile(
        "ds_read_b64_tr_b16 %0, %8 offset:0\n\t"
        "ds_read_b64_tr_b16 %1, %8 offset:512\n\t"
        "ds_read_b64_tr_b16 %2, %8 offset:1024\n\t"
        "ds_read_b64_tr_b16 %3, %8 offset:1536\n\t"
        "ds_read_b64_tr_b16 %4, %8 offset:2048\n\t"
        "ds_read_b64_tr_b16 %5, %8 offset:2560\n\t"
        "ds_read_b64_tr_b16 %6, %8 offset:3072\n\t"
        "ds_read_b64_tr_b16 %7, %8 offset:3584"
        : "=&v"(t0), "=&v"(t1), "=&v"(t2), "=&v"(t3),
          "=&v"(t4), "=&v"(t5), "=&v"(t6), "=&v"(t7)
        : "v"(va)
        : "memory");
    asm volatile("s_waitcnt lgkmcnt(0)" ::: "memory");
    __builtin_amdgcn_sched_barrier(0);

    acc2[0] = MFMA16(P.s, cat4(t0, t1), acc2[0]);
    acc2[1] = MFMA16(P.s, cat4(t2, t3), acc2[1]);
    acc2[2] = MFMA16(P.s, cat4(t4, t5), acc2[2]);
    acc2[3] = MFMA16(P.s, cat4(t6, t7), acc2[3]);
    acc2[4] = MFMA16(P.s, vb4, acc2[4]);

    // ---- write-late: next-tile ks conversion + fourier + hk, and v tile ----
    if (it < 15 && tid < 512) {
      float part = (kvn[0]*kvn[0] + kvn[1]*kvn[1] + kvn[2]*kvn[2] + kvn[3]*kvn[3]) * NORM2;
      s16x4 o;
#pragma unroll
      for (int i = 0; i < 4; ++i) o[i] = (short)f2bf(kvn[i]);
      *reinterpret_cast<s16x4*>(&sbuf[nxt][row * 256 + ((8 * seg) ^ s4)]) = o;
      if (seg < 8) {
        float ph = svn * wv;
        float e = issin ? sinf(ph) : cosf(ph);
        part += e * e;
        *reinterpret_cast<unsigned short*>(&sbuf[nxt][row * 256 + ((128 + 2 * seg) ^ s4)]) = f2bf(e);
      }
#pragma unroll
      for (int m = 1; m < 16; m <<= 1) part += __shfl_xor(part, m, 64);
      if (seg == 0) hk_sh[nxt][row] = 0.5f * part + LN16;
      uint2 vp = make_uint2(pk2(vvn[0], vvn[1]), pk2(vvn[2], vvn[3]));
      *reinterpret_cast<uint2*>(&sbuf[nxt][vwo]) = vp;
    }
    __syncthreads();
  }

#pragma unroll
  for (int ne = 0; ne < 5; ++ne)
#pragma unroll
    for (int r = 0; r < 4; ++r) {
      int m = 16 * w + 4 * l4 + r;
      parts[(((size_t)split * 32 + bh) * MM + m) * EE + l15 + 16 * ne] = acc2[ne][r];
    }
}

// ---------------------------------------------------------------------------
// reduce 8 splits -> b1F fragment-major [bh][ks(8)][ne(5)][lane][8] bf16
// ---------------------------------------------------------------------------
__global__ __launch_bounds__(256) void reduce_t(const float* __restrict__ parts,
                                                unsigned short* __restrict__ b1F) {
  int bh = blockIdx.x;   // 32
  int mc = blockIdx.y;   // 4 (64 m each)
  __shared__ float s[64 * 80];
  size_t base = ((size_t)bh * MM + mc * 64) * EE;
  for (int o = threadIdx.x; o < 64 * 80; o += 256) {
    float sum = 0.f;
#pragma unroll
    for (int sp = 0; sp < NSPLIT; ++sp)
      sum += parts[(size_t)sp * 32 * MM * EE + base + o];
    s[o] = sum;
  }
  __syncthreads();
  int t = threadIdx.x, l = t & 63, kl = (t >> 6) & 1, rep = t >> 7;
  int l15 = l & 15, l4 = l >> 4;
  int nelo = rep ? 3 : 0, nehi = rep ? 5 : 3;
  for (int ne = nelo; ne < nehi; ++ne) {
    s16x8 o;
#pragma unroll
    for (int j = 0; j < 8; ++j) {
      int ml = 32 * kl + 16 * (j >> 2) + 4 * l4 + (j & 3);
      o[j] = (short)f2bf(s[ml * 80 + l15 + 16 * ne]);
    }
    int ks = mc * 2 + kl;
    *reinterpret_cast<s16x8*>(
        b1F + (((size_t)bh * 8 + ks) * 5 + ne) * 64 * 8 + (size_t)l * 8) = o;
  }
}

// ---------------------------------------------------------------------------
// F2: fused {qs->frag + fourier + hq} + phi_q GEMM + exp + output GEMM.
// 1024 threads (16 waves x 32 q), grid (32 bh, 8 qc). (unchanged from R10)
// ---------------------------------------------------------------------------
__global__ __launch_bounds__(1024, 1) void f2_k(
    const float* __restrict__ qs, const float* __restrict__ qs_s,
    const float* __restrict__ W, const float* __restrict__ a,
    const unsigned short* __restrict__ projF,
    const unsigned short* __restrict__ b1F, float* __restrict__ out) {
  __shared__ unsigned short pf_lds[24576];   // 48 KB
  __shared__ unsigned short b1_lds[20480];   // 40 KB

  int bh = blockIdx.x, qc = blockIdx.y;
  int b = bh >> 3, h = bh & 7;
  int tid = threadIdx.x;
  int w = tid >> 6, l = tid & 63;
  int l15 = l & 15, l4 = l >> 4;
  int qb = qc * 512 + w * 32;
  const unsigned short* b1b = b1F + (size_t)bh * 8 * 5 * 64 * 8;
  float ah = a[h];

  {
    const u32x4* g1 = reinterpret_cast<const u32x4*>(projF);
    u32x4* s1 = reinterpret_cast<u32x4*>(pf_lds);
#pragma unroll
    for (int i = 0; i < 3; ++i) s1[i * 1024 + tid] = g1[i * 1024 + tid];
    const u32x4* g2 = reinterpret_cast<const u32x4*>(b1b);
    u32x4* s2 = reinterpret_cast<u32x4*>(b1_lds);
    s2[tid] = g2[tid];
    s2[1024 + tid] = g2[1024 + tid];
    if (tid < 512) s2[2048 + tid] = g2[2048 + tid];
  }

  s16x8 xq[2][3];
#pragma unroll
  for (int qt = 0; qt < 2; ++qt) {
    int qrow = qb + 16 * qt + l15;
    const float* qr = qs + ((size_t)(b * LLEN + qrow) * HH + h) * 64;
    float part = 0.f;
#pragma unroll
    for (int xs = 0; xs < 2; ++xs) {
      f32x4 u0 = *reinterpret_cast<const f32x4*>(qr + 32 * xs + 8 * l4);
      f32x4 u1 = *reinterpret_cast<const f32x4*>(qr + 32 * xs + 8 * l4 + 4);
      s16x8 fr;
#pragma unroll
      for (int i = 0; i < 4; ++i) {
        part += u0[i] * u0[i] + u1[i] * u1[i];
        fr[i] = (short)f2bf(u0[i]);
        fr[4 + i] = (short)f2bf(u1[i]);
      }
      xq[qt][xs] = fr;
    }
    part *= NORM2;
    s16x8 fx = {};
    if (l4 == 0) {
      float sv = qs_s[(size_t)b * LLEN + qrow] * TWO_PI_F;
#pragma unroll
      for (int j = 0; j < 8; ++j) {
        int dim = 8 * h + j;
        float ph = sv * W[dim & 31];
        float e = (dim < 32) ? sinf(ph) : cosf(ph);
        e *= ah;
        part += e * e;
        fx[j] = (short)f2bf(e);
      }
    }
    part += __shfl_xor(part, 16, 64);
    part += __shfl_xor(part, 32, 64);
    if (l4 == 1) fx[0] = (short)f2bf(0.5f * part + LN16);
    xq[qt][2] = fx;
  }
  __syncthreads();

  f32x4 acc3[2][5] = {};
#pragma unroll
  for (int ks = 0; ks < 8; ++ks) {
    f32x4 a0 = {}, b0 = {}, a1 = {}, b1 = {};
    __builtin_amdgcn_s_setprio(1);
#pragma unroll
    for (int xs = 0; xs < 3; ++xs) {
      s16x8 p0 = *reinterpret_cast<const s16x8*>(pf_lds + (((2 * ks) * 3 + xs) * 64 + l) * 8);
      s16x8 p1 = *reinterpret_cast<const s16x8*>(pf_lds + (((2 * ks + 1) * 3 + xs) * 64 + l) * 8);
      a0 = MFMA16(p0, xq[0][xs], a0);
      b0 = MFMA16(p1, xq[0][xs], b0);
      a1 = MFMA16(p0, xq[1][xs], a1);
      b1 = MFMA16(p1, xq[1][xs], b1);
    }
    __builtin_amdgcn_s_setprio(0);
    union { unsigned int u[4]; s16x8 s; } Pa, Pb;
    Pa.u[0] = pk2(__expf(a0[0]), __expf(a0[1]));
    Pa.u[1] = pk2(__expf(a0[2]), __expf(a0[3]));
    Pa.u[2] = pk2(__expf(b0[0]), __expf(b0[1]));
    Pa.u[3] = pk2(__expf(b0[2]), __expf(b0[3]));
    Pb.u[0] = pk2(__expf(a1[0]), __expf(a1[1]));
    Pb.u[1] = pk2(__expf(a1[2]), __expf(a1[3]));
    Pb.u[2] = pk2(__expf(b1[0]), __expf(b1[1]));
    Pb.u[3] = pk2(__expf(b1[2]), __expf(b1[3]));
    __builtin_amdgcn_s_setprio(1);
#pragma unroll
    for (int ne = 0; ne < 5; ++ne) {
      s16x8 vb = *reinterpret_cast<const s16x8*>(b1_lds + ((ks * 5 + ne) * 64 + l) * 8);
      acc3[0][ne] = MFMA16(Pa.s, vb, acc3[0][ne]);
      acc3[1][ne] = MFMA16(Pb.s, vb, acc3[1][ne]);
    }
    __builtin_amdgcn_s_setprio(0);
  }
#pragma unroll
  for (int qt = 0; qt < 2; ++qt) {
    float inv[4];
#pragma unroll
    for (int r = 0; r < 4; ++r) {
      float den = __shfl(acc3[qt][4][r], 16 * l4, 64);
      den = den < EPSV ? EPSV : den;
      inv[r] = 1.0f / den;
    }
#pragma unroll
    for (int ne = 0; ne < 4; ++ne)
#pragma unroll
      for (int r = 0; r < 4; ++r)
        out[((size_t)(b * LLEN + qb + 16 * qt + 4 * l4 + r) * HH + h) * 64 + l15 + 16 * ne] =
            acc3[qt][ne][r] * inv[r];
  }
}

// ---------------------------------------------------------------------------
extern "C" void kernel_launch(void* const* d_in, const int* in_sizes, int n_in,
                              void* d_out, int out_size, void* d_ws, size_t ws_size,
                              hipStream_t stream) {
  const float* qs   = (const float*)d_in[0];
  const float* ks   = (const float*)d_in[1];
  const float* vs   = (const float*)d_in[2];
  const float* qs_s = (const float*)d_in[3];
  const float* ks_s = (const float*)d_in[4];
  const float* W    = (const float*)d_in[5];
  const float* proj = (const float*)d_in[6];
  const float* a    = (const float*)d_in[7];
  float* out = (float*)d_out;

  char* ws = (char*)d_ws;
  unsigned short* projF = (unsigned short*)(ws + OFF_PROJF);
  float*          parts = (float*)(ws + OFF_PARTS);
  unsigned short* b1F   = (unsigned short*)(ws + OFF_B1F);

  prep_projF<<<1, 256, 0, stream>>>(proj, projF);
  f1_k<<<dim3(32, NSPLIT), 1024, 0, stream>>>(ks, ks_s, vs, W, projF, parts);
  reduce_t<<<dim3(32, 4), 256, 0, stream>>>(parts, b1F);
  f2_k<<<dim3(32, 8), 1024, 0, stream>>>(qs, qs_s, W, a, projF, b1F, out);
}